// Round 4
// baseline (3265.406 us; speedup 1.0000x reference)
//
#include <hip/hip_runtime.h>
#include <math.h>

// SchNet forward, MI355X. Round 4: GEMM restructured for the latency-bound
// regime diagnosed in round 3 (913 GB/s over 97MB = the whole 109us):
//  - 128x64 tiles -> 800 blocks (was 395), LDS 30KB -> 4 blocks/CU
//  - XCD-grouped swizzle: the 10 N-tiles sharing an A-slab run on the same
//    XCD back-to-back -> A fetched ~once from HBM (FETCH 72->~30MB)
//  - register prefetch of chunk k+1 overlapping MFMA of chunk k
// Split-bf16 MFMA (r3), CSR gather (r2), filter table + lerp (r1) retained.

#define N_ATOMS 10000
#define E_EDGES 64000
#define B_MOLS  128
#define H_DIM   600
#define G_DIM   50
#define L_LAYERS 6
#define M_TAB   2048
#define DMAX    8.67f
#define LOG2C   0.69314718056f

#define TM 128
#define TN 64
#define TK 32
#define SA 40          // LDS row stride in shorts (80B; b128-aligned, 2-way banks)

typedef __attribute__((ext_vector_type(8))) short bf16x8;
typedef __attribute__((ext_vector_type(4))) float f32x4;

__device__ __forceinline__ float sspf(float x) {
    return fmaxf(x, 0.0f) + log1pf(expf(-fabsf(x))) - LOG2C;
}

__device__ __forceinline__ short f2bf(float x) {
    unsigned u = __float_as_uint(x);
    unsigned r = (u + 0x7FFF + ((u >> 16) & 1)) >> 16;   // RNE
    return (short)r;
}
__device__ __forceinline__ float bf2f(short h) {
    return __uint_as_float(((unsigned)(unsigned short)h) << 16);
}
__device__ __forceinline__ void split2(float x, short& hi, short& lo) {
    hi = f2bf(x);
    lo = f2bf(x - bf2f(hi));
}

__device__ __forceinline__ void load_pair(const short* __restrict__ Ph,
                                          const short* __restrict__ Pl,
                                          int row, int ld, int gk, int K,
                                          int rowmax, short4& vh, short4& vl)
{
    vh = {0, 0, 0, 0}; vl = {0, 0, 0, 0};
    if (row < rowmax) {
        const short* ph = Ph + (size_t)row * ld + gk;
        const short* pl = Pl + (size_t)row * ld + gk;
        if (gk + 3 < K) {
            vh = *(const short4*)ph; vl = *(const short4*)pl;
        } else {
            if (gk + 0 < K) { vh.x = ph[0]; vl.x = pl[0]; }
            if (gk + 1 < K) { vh.y = ph[1]; vl.y = pl[1]; }
            if (gk + 2 < K) { vh.z = ph[2]; vl.z = pl[2]; }
        }
    }
}

// ---------------------------------------------------------------- MFMA GEMM
// out[Ma,Nc] = op(A[Ma,K] @ B[K,Nc] + bias); A as bf16 hi/lo [Ma][lda],
// B TRANSPOSED as bf16 hi/lo [Nc][ldb]. Grid: 1D, Yslots*NT blocks with
// Yslots = ceil(MB/8)*8; swizzle keeps same-A-slab blocks on one XCD.
template<bool BIAS, bool ACT, bool ACCUM, bool WF32, bool WSPLIT>
__global__ __launch_bounds__(256, 4)
void gemm_mfma(const short* __restrict__ Ah, const short* __restrict__ Al, int lda,
               const short* __restrict__ Bh, const short* __restrict__ Bl, int ldb,
               const float* __restrict__ bias,
               float* __restrict__ outF, short* __restrict__ outH,
               short* __restrict__ outL,
               int Ma, int K, int Nc)
{
    const int NT = (Nc + TN - 1) / TN;
    const int f = blockIdx.x;
    const int xcd = f & 7, s = f >> 3;
    const int n0 = (s % NT) * TN;
    const int m0 = (xcd + 8 * (s / NT)) * TM;
    if (m0 >= Ma) return;

    __shared__ __align__(16) short As[2][TM * SA];   // [hi/lo][m][k]
    __shared__ __align__(16) short Bs[2][TN * SA];   // [hi/lo][n][k]

    const int tid = threadIdx.x;
    const int lane = tid & 63, wid = tid >> 6;
    const int wm = (wid >> 1) * 64, wn = (wid & 1) * 32;
    const int l15 = lane & 15, quad = lane >> 4;

    const int srow = tid >> 3;          // 0..31 (+32*pass)
    const int skk  = (tid & 7) << 2;    // 0,4,..,28

    f32x4 acc[4][2];
    #pragma unroll
    for (int i = 0; i < 4; ++i)
        #pragma unroll
        for (int j = 0; j < 2; ++j)
            acc[i][j] = (f32x4){0.f, 0.f, 0.f, 0.f};

    short4 ra_h[4], ra_l[4], rb_h[2], rb_l[2];

    // prefetch chunk 0
    #pragma unroll
    for (int p = 0; p < 4; ++p)
        load_pair(Ah, Al, m0 + p * 32 + srow, lda, skk, K, Ma, ra_h[p], ra_l[p]);
    #pragma unroll
    for (int p = 0; p < 2; ++p)
        load_pair(Bh, Bl, n0 + p * 32 + srow, ldb, skk, K, Nc, rb_h[p], rb_l[p]);

    for (int k0 = 0; k0 < K; k0 += TK) {
        // store prefetched chunk to LDS
        #pragma unroll
        for (int p = 0; p < 4; ++p) {
            int m = p * 32 + srow;
            *(short4*)&As[0][m * SA + skk] = ra_h[p];
            *(short4*)&As[1][m * SA + skk] = ra_l[p];
        }
        #pragma unroll
        for (int p = 0; p < 2; ++p) {
            int n = p * 32 + srow;
            *(short4*)&Bs[0][n * SA + skk] = rb_h[p];
            *(short4*)&Bs[1][n * SA + skk] = rb_l[p];
        }
        __syncthreads();

        // fragment reads
        bf16x8 a_h[4], a_l[4], b_h[2], b_l[2];
        #pragma unroll
        for (int mi = 0; mi < 4; ++mi) {
            int row = wm + mi * 16 + l15;
            a_h[mi] = *(const bf16x8*)&As[0][row * SA + quad * 8];
            a_l[mi] = *(const bf16x8*)&As[1][row * SA + quad * 8];
        }
        #pragma unroll
        for (int ni = 0; ni < 2; ++ni) {
            int col = wn + ni * 16 + l15;
            b_h[ni] = *(const bf16x8*)&Bs[0][col * SA + quad * 8];
            b_l[ni] = *(const bf16x8*)&Bs[1][col * SA + quad * 8];
        }

        // prefetch next chunk (overlaps MFMA below)
        int kn = k0 + TK;
        if (kn < K) {
            #pragma unroll
            for (int p = 0; p < 4; ++p)
                load_pair(Ah, Al, m0 + p * 32 + srow, lda, kn + skk, K, Ma,
                          ra_h[p], ra_l[p]);
            #pragma unroll
            for (int p = 0; p < 2; ++p)
                load_pair(Bh, Bl, n0 + p * 32 + srow, ldb, kn + skk, K, Nc,
                          rb_h[p], rb_l[p]);
        }

        #pragma unroll
        for (int mi = 0; mi < 4; ++mi)
            #pragma unroll
            for (int ni = 0; ni < 2; ++ni) {
                acc[mi][ni] = __builtin_amdgcn_mfma_f32_16x16x32_bf16(
                    a_h[mi], b_h[ni], acc[mi][ni], 0, 0, 0);
                acc[mi][ni] = __builtin_amdgcn_mfma_f32_16x16x32_bf16(
                    a_h[mi], b_l[ni], acc[mi][ni], 0, 0, 0);
                acc[mi][ni] = __builtin_amdgcn_mfma_f32_16x16x32_bf16(
                    a_l[mi], b_h[ni], acc[mi][ni], 0, 0, 0);
            }
        __syncthreads();
    }

    // epilogue: C/D layout col = lane&15, row = quad*4 + r
    #pragma unroll
    for (int mi = 0; mi < 4; ++mi) {
        #pragma unroll
        for (int r = 0; r < 4; ++r) {
            int row = m0 + wm + mi * 16 + quad * 4 + r;
            if (row >= Ma) continue;
            #pragma unroll
            for (int ni = 0; ni < 2; ++ni) {
                int col = n0 + wn + ni * 16 + l15;
                if (col >= Nc) continue;
                float v = acc[mi][ni][r];
                if constexpr (BIAS) v += bias[col];
                if constexpr (ACT)  v = sspf(v);
                size_t idx = (size_t)row * Nc + col;
                if constexpr (ACCUM) v += outF[idx];
                if constexpr (WF32)  outF[idx] = v;
                if constexpr (WSPLIT) {
                    short hh, ll; split2(v, hh, ll);
                    outH[idx] = hh; outL[idx] = ll;
                }
            }
        }
    }
}

static inline dim3 mfma_grid(int Ma, int Nc) {
    int MB = (Ma + TM - 1) / TM;
    int NT = (Nc + TN - 1) / TN;
    int Ys = ((MB + 7) / 8) * 8;
    return dim3(Ys * NT);
}

// ---------------------------------------------------------------- fp32 GEMM (pool only)
#define BM 64
#define BN 64
#define BK 16
template<bool BIAS>
__global__ __launch_bounds__(256)
void gemm_k(const float* __restrict__ A, int lda,
            const float* __restrict__ W,
            const float* __restrict__ bias,
            float* __restrict__ out,
            int Ma, int K, int Nc)
{
    __shared__ __align__(16) float Asd[BK][BM];
    __shared__ __align__(16) float Bsd[BK][BN];
    const int tid = threadIdx.x;
    const int tx = tid & 15, ty = tid >> 4;
    const int m0 = blockIdx.y * BM, n0 = blockIdx.x * BN;
    const int ar = tid >> 2, ac = (tid & 3) << 2;
    const int br = tid >> 4, bc = (tid & 15) << 2;
    float acc[4][4] = {};
    for (int k0 = 0; k0 < K; k0 += BK) {
        {
            int row = m0 + ar, col = k0 + ac;
            float4 v = make_float4(0.f, 0.f, 0.f, 0.f);
            if (row < Ma) {
                const float* ap = A + (size_t)row * lda + col;
                if (col + 3 < K) v = *(const float4*)ap;
                else {
                    if (col + 0 < K) v.x = ap[0];
                    if (col + 1 < K) v.y = ap[1];
                    if (col + 2 < K) v.z = ap[2];
                }
            }
            Asd[ac + 0][ar] = v.x; Asd[ac + 1][ar] = v.y;
            Asd[ac + 2][ar] = v.z; Asd[ac + 3][ar] = v.w;
        }
        {
            int row = k0 + br, col = n0 + bc;
            float4 v = make_float4(0.f, 0.f, 0.f, 0.f);
            if (row < K && col + 3 < Nc)
                v = *(const float4*)(W + (size_t)row * Nc + col);
            *(float4*)&Bsd[br][bc] = v;
        }
        __syncthreads();
        #pragma unroll
        for (int kk = 0; kk < BK; ++kk) {
            float4 a4 = *(const float4*)&Asd[kk][ty << 2];
            float4 b4 = *(const float4*)&Bsd[kk][tx << 2];
            float av[4] = {a4.x, a4.y, a4.z, a4.w};
            float bv[4] = {b4.x, b4.y, b4.z, b4.w};
            #pragma unroll
            for (int i = 0; i < 4; ++i)
                #pragma unroll
                for (int j = 0; j < 4; ++j)
                    acc[i][j] = fmaf(av[i], bv[j], acc[i][j]);
        }
        __syncthreads();
    }
    #pragma unroll
    for (int i = 0; i < 4; ++i) {
        int row = m0 + (ty << 2) + i;
        if (row >= Ma) continue;
        #pragma unroll
        for (int j = 0; j < 4; ++j) {
            int col = n0 + (tx << 2) + j;
            if (col >= Nc) continue;
            float v = acc[i][j];
            if constexpr (BIAS) v += bias[col];
            out[(size_t)row * Nc + col] = v;
        }
    }
}

// ---------------------------------------------------------------- weight prep
__global__ __launch_bounds__(256)
void wts_w1_k(const float* __restrict__ w_all, short* __restrict__ oh,
              short* __restrict__ ol)
{
    __shared__ short th[64][65], tl[64][65];
    const int layer = blockIdx.z;
    const float* w = w_all + (size_t)layer * G_DIM * H_DIM;
    short* ohz = oh + (size_t)layer * H_DIM * 64;
    short* olz = ol + (size_t)layer * H_DIM * 64;
    const int n0 = blockIdx.y * 64;
    const int tid = threadIdx.x;
    #pragma unroll
    for (int p = 0; p < 4; ++p) {
        int k = p * 16 + (tid >> 4);
        int n4 = (tid & 15) << 2;
        float4 v = make_float4(0.f, 0.f, 0.f, 0.f);
        if (k < G_DIM && n0 + n4 + 3 < H_DIM)
            v = *(const float4*)(w + (size_t)k * H_DIM + n0 + n4);
        short hh, ll;
        split2(v.x, hh, ll); th[n4 + 0][k] = hh; tl[n4 + 0][k] = ll;
        split2(v.y, hh, ll); th[n4 + 1][k] = hh; tl[n4 + 1][k] = ll;
        split2(v.z, hh, ll); th[n4 + 2][k] = hh; tl[n4 + 2][k] = ll;
        split2(v.w, hh, ll); th[n4 + 3][k] = hh; tl[n4 + 3][k] = ll;
    }
    __syncthreads();
    #pragma unroll
    for (int p = 0; p < 4; ++p) {
        int n = p * 16 + (tid >> 4);
        int k4 = (tid & 15) << 2;
        if (n0 + n >= H_DIM) continue;
        short4 sh = { th[n][k4], th[n][k4 + 1], th[n][k4 + 2], th[n][k4 + 3] };
        short4 sl = { tl[n][k4], tl[n][k4 + 1], tl[n][k4 + 2], tl[n][k4 + 3] };
        *(short4*)(ohz + (size_t)(n0 + n) * 64 + k4) = sh;
        *(short4*)(olz + (size_t)(n0 + n) * 64 + k4) = sl;
    }
}

__global__ __launch_bounds__(256)
void wts_big_k(const float* __restrict__ w2, const float* __restrict__ l1,
               const float* __restrict__ l2, const float* __restrict__ iw,
               short* __restrict__ oh2, short* __restrict__ ol2,
               short* __restrict__ oh1, short* __restrict__ ol1,
               short* __restrict__ ohl2, short* __restrict__ oll2,
               short* __restrict__ ohi, short* __restrict__ oli)
{
    __shared__ short th[64][65], tl[64][65];
    const int z = blockIdx.z, type = z / L_LAYERS, layer = z % L_LAYERS;
    const float* w; short* oh; short* ol;
    if (type == 0)      { w = w2; oh = oh2; ol = ol2; }
    else if (type == 1) { w = l1; oh = oh1; ol = ol1; }
    else if (type == 2) { w = l2; oh = ohl2; ol = oll2; }
    else                { w = iw; oh = ohi; ol = oli; }
    w  += (size_t)layer * H_DIM * H_DIM;
    oh += (size_t)layer * H_DIM * H_DIM;
    ol += (size_t)layer * H_DIM * H_DIM;
    const int k0 = blockIdx.x * 64, n0 = blockIdx.y * 64;
    const int tid = threadIdx.x;
    #pragma unroll
    for (int p = 0; p < 4; ++p) {
        int k = p * 16 + (tid >> 4);
        int n4 = (tid & 15) << 2;
        float4 v = make_float4(0.f, 0.f, 0.f, 0.f);
        if (k0 + k < H_DIM && n0 + n4 + 3 < H_DIM)
            v = *(const float4*)(w + (size_t)(k0 + k) * H_DIM + n0 + n4);
        short hh, ll;
        split2(v.x, hh, ll); th[n4 + 0][k] = hh; tl[n4 + 0][k] = ll;
        split2(v.y, hh, ll); th[n4 + 1][k] = hh; tl[n4 + 1][k] = ll;
        split2(v.z, hh, ll); th[n4 + 2][k] = hh; tl[n4 + 2][k] = ll;
        split2(v.w, hh, ll); th[n4 + 3][k] = hh; tl[n4 + 3][k] = ll;
    }
    __syncthreads();
    #pragma unroll
    for (int p = 0; p < 4; ++p) {
        int n = p * 16 + (tid >> 4);
        int k4 = (tid & 15) << 2;
        if (n0 + n >= H_DIM || k0 + k4 >= H_DIM) continue;
        short4 sh = { th[n][k4], th[n][k4 + 1], th[n][k4 + 2], th[n][k4 + 3] };
        short4 sl = { tl[n][k4], tl[n][k4 + 1], tl[n][k4 + 2], tl[n][k4 + 3] };
        *(short4*)(oh + (size_t)(n0 + n) * H_DIM + k0 + k4) = sh;
        *(short4*)(ol + (size_t)(n0 + n) * H_DIM + k0 + k4) = sl;
    }
}

// ---------------------------------------------------------------- helpers
__global__ __launch_bounds__(256)
void init_h_k(const int* __restrict__ z, const float* __restrict__ emb,
              float* __restrict__ h, short* __restrict__ hh, short* __restrict__ hl)
{
    int t = blockIdx.x * 256 + threadIdx.x;
    const int QH = H_DIM / 4;
    if (t >= N_ATOMS * QH) return;
    int i = t / QH;
    int q = (t - i * QH) << 2;
    size_t idx = (size_t)i * H_DIM + q;
    float4 v = *(const float4*)(emb + (size_t)z[i] * H_DIM + q);
    *(float4*)(h + idx) = v;
    short4 sh, sl;
    split2(v.x, sh.x, sl.x); split2(v.y, sh.y, sl.y);
    split2(v.z, sh.z, sl.z); split2(v.w, sh.w, sl.w);
    *(short4*)(hh + idx) = sh;
    *(short4*)(hl + idx) = sl;
}

__global__ __launch_bounds__(256)
void edge_geom_k(const float* __restrict__ pos, const int* __restrict__ src,
                 const int* __restrict__ dst, float4* __restrict__ einfo)
{
    int e = blockIdx.x * 256 + threadIdx.x;
    if (e >= E_EDGES) return;
    int s = src[e], d0 = dst[e];
    float dx = pos[s * 3 + 0] - pos[d0 * 3 + 0];
    float dy = pos[s * 3 + 1] - pos[d0 * 3 + 1];
    float dz = pos[s * 3 + 2] - pos[d0 * 3 + 2];
    float dist = sqrtf(dx * dx + dy * dy + dz * dz + 1e-12f);
    float cc = 0.5f * (cosf(dist * 0.31415926535f) + 1.0f);
    float u = dist * ((float)(M_TAB - 1) / DMAX);
    u = fminf(fmaxf(u, 0.0f), (float)(M_TAB - 1) - 0.001f);
    int i0 = (int)u;
    float f = u - (float)i0;
    einfo[e] = make_float4(__int_as_float(s * H_DIM),
                           __int_as_float(i0 * H_DIM),
                           f * cc, cc);
}

__global__ __launch_bounds__(256)
void rbf_tab_k(short* __restrict__ rh, short* __restrict__ rl)
{
    int t = blockIdx.x * 256 + threadIdx.x;
    if (t >= M_TAB * 64) return;
    int i = t >> 6, g = t & 63;
    float v = 0.0f;
    if (g < G_DIM) {
        float dg  = (float)i * (DMAX / (float)(M_TAB - 1));
        float off = (float)g * (10.0f / 49.0f);
        float x = dg - off;
        const float coeff = -0.5f * (49.0f / 10.0f) * (49.0f / 10.0f);
        v = expf(coeff * x * x);
    }
    short hh, ll; split2(v, hh, ll);
    rh[t] = hh; rl[t] = ll;
}

// ---------------------------------------------------------------- CSR build
__global__ __launch_bounds__(256)
void hist_k(const int* __restrict__ dst, int* __restrict__ deg)
{
    int e = blockIdx.x * 256 + threadIdx.x;
    if (e >= E_EDGES) return;
    atomicAdd(&deg[dst[e]], 1);
}

__global__ __launch_bounds__(1024)
void scan_k(const int* __restrict__ deg, int* __restrict__ rowptr)
{
    __shared__ int sums[1024];
    int tid = threadIdx.x;
    const int CHUNK = (N_ATOMS + 1023) / 1024;
    int base = tid * CHUNK;
    int local[16];
    int s = 0;
    #pragma unroll
    for (int c = 0; c < 16; ++c) {
        if (c >= CHUNK) break;
        int idx = base + c;
        local[c] = s;
        s += (idx < N_ATOMS) ? deg[idx] : 0;
    }
    sums[tid] = s;
    __syncthreads();
    for (int off = 1; off < 1024; off <<= 1) {
        int v = (tid >= off) ? sums[tid - off] : 0;
        __syncthreads();
        sums[tid] += v;
        __syncthreads();
    }
    int prefix = (tid > 0) ? sums[tid - 1] : 0;
    #pragma unroll
    for (int c = 0; c < 16; ++c) {
        if (c >= CHUNK) break;
        int idx = base + c;
        if (idx <= N_ATOMS) rowptr[idx] = prefix + local[c];
    }
    if (tid == 1023) rowptr[N_ATOMS] = sums[1023];
}

__global__ __launch_bounds__(256)
void fill_k(const int* __restrict__ dst, const float4* __restrict__ einfo,
            const int* __restrict__ rowptr, int* __restrict__ cursor,
            float4* __restrict__ esorted)
{
    int e = blockIdx.x * 256 + threadIdx.x;
    if (e >= E_EDGES) return;
    int d0 = dst[e];
    int pos = rowptr[d0] + atomicAdd(&cursor[d0], 1);
    esorted[pos] = einfo[e];
}

// ---------------------------------------------------------------- gather
__global__ __launch_bounds__(256)
void gather_k(const float* __restrict__ y, const float* __restrict__ wt,
              const int* __restrict__ rowptr, const float4* __restrict__ esorted,
              short* __restrict__ aggH, short* __restrict__ aggL)
{
    int t = blockIdx.x * 256 + threadIdx.x;
    const int QH = H_DIM / 4;
    if (t >= N_ATOMS * QH) return;
    int i = t / QH;
    int q = (t - i * QH) << 2;
    int j0 = rowptr[i], j1 = rowptr[i + 1];
    float4 acc = make_float4(0.f, 0.f, 0.f, 0.f);
    for (int j = j0; j < j1; ++j) {
        float4 ei = esorted[j];
        int srow = __float_as_int(ei.x);
        int wrow = __float_as_int(ei.y);
        float fc = ei.z, cc = ei.w;
        const float4 yv = *(const float4*)(y + srow + q);
        const float4 w0 = *(const float4*)(wt + wrow + q);
        const float4 w1 = *(const float4*)(wt + wrow + H_DIM + q);
        acc.x += yv.x * (w0.x * cc + fc * (w1.x - w0.x));
        acc.y += yv.y * (w0.y * cc + fc * (w1.y - w0.y));
        acc.z += yv.z * (w0.z * cc + fc * (w1.z - w0.z));
        acc.w += yv.w * (w0.w * cc + fc * (w1.w - w0.w));
    }
    short4 sh, sl;
    split2(acc.x, sh.x, sl.x); split2(acc.y, sh.y, sl.y);
    split2(acc.z, sh.z, sl.z); split2(acc.w, sh.w, sl.w);
    size_t idx = (size_t)i * H_DIM + q;
    *(short4*)(aggH + idx) = sh;
    *(short4*)(aggL + idx) = sl;
}

// ---------------------------------------------------------------- pool
__global__ __launch_bounds__(256)
void pool_sum_k(const float* __restrict__ h, const int* __restrict__ batch,
                float* __restrict__ sums)
{
    int t = blockIdx.x * 256 + threadIdx.x;
    const int QH = H_DIM / 4;
    if (t >= N_ATOMS * QH) return;
    int i = t / QH;
    int q = (t - i * QH) << 2;
    int b = batch[i];
    const float4 hv = *(const float4*)(h + (size_t)i * H_DIM + q);
    float* sp = sums + (size_t)b * H_DIM + q;
    atomicAdd(sp + 0, hv.x);
    atomicAdd(sp + 1, hv.y);
    atomicAdd(sp + 2, hv.z);
    atomicAdd(sp + 3, hv.w);
}

__global__ __launch_bounds__(256)
void cnt_k(const int* __restrict__ batch, float* __restrict__ cnt)
{
    int i = blockIdx.x * 256 + threadIdx.x;
    if (i >= N_ATOMS) return;
    atomicAdd(&cnt[batch[i]], 1.0f);
}

__global__ __launch_bounds__(256)
void pool_div_k(float* __restrict__ sums, const float* __restrict__ cnt)
{
    int t = blockIdx.x * 256 + threadIdx.x;
    if (t >= B_MOLS * H_DIM) return;
    sums[t] /= fmaxf(cnt[t / H_DIM], 1.0f);
}

// ---------------------------------------------------------------- launch
extern "C" void kernel_launch(void* const* d_in, const int* in_sizes, int n_in,
                              void* d_out, int out_size, void* d_ws, size_t ws_size,
                              hipStream_t stream)
{
    const int*   z      = (const int*)  d_in[0];
    const float* pos    = (const float*)d_in[1];
    const int*   batch  = (const int*)  d_in[2];
    const int*   eidx   = (const int*)  d_in[3];
    const float* emb    = (const float*)d_in[4];
    const float* mlp_w1 = (const float*)d_in[5];
    const float* mlp_b1 = (const float*)d_in[6];
    const float* mlp_w2 = (const float*)d_in[7];
    const float* mlp_b2 = (const float*)d_in[8];
    const float* lin1_w = (const float*)d_in[9];
    const float* lin2_w = (const float*)d_in[10];
    const float* lin2_b = (const float*)d_in[11];
    const float* intw   = (const float*)d_in[12];
    const float* intb   = (const float*)d_in[13];
    const float* poolw  = (const float*)d_in[14];
    const float* poolb  = (const float*)d_in[15];

    float* ws = (float*)d_ws;
    float*  h       = ws;                                   // 6,000,000 f
    float*  y1      = ws + 6000000;                         // 6,000,000 f
    short*  t_hi    = (short*)y1;                           // alias (post-gather)
    short*  t_lo    = t_hi + 6000000;
    short*  h_hi    = (short*)(ws + 12000000);
    short*  h_lo    = (short*)(ws + 15000000);
    short*  agg_hi  = (short*)(ws + 18000000);
    short*  agg_lo  = (short*)(ws + 21000000);
    short*  ttab_hi = (short*)(ws + 24000000);
    short*  ttab_lo = (short*)(ws + 24614400);
    float*  wtab    = ws + 25228800;
    short*  rtab_hi = (short*)(ws + 26457600);
    short*  rtab_lo = (short*)(ws + 26523136);
    short*  wt_hi   = (short*)(ws + 26588672);
    short*  wt_lo   = (short*)(ws + 31023872);
    float4* einfo   = (float4*)(ws + 35459072);
    float4* esorted = (float4*)(ws + 35715072);
    float*  sums    = ws + 35971072;
    float*  cnt     = ws + 36047872;
    int*    deg     = (int*)(ws + 36048000);
    int*    cursor  = (int*)(ws + 36058000);
    int*    rowptr  = (int*)(ws + 36068000);
    // total ~36.08M floats = 144.3 MB

    short* w1t_h = wt_hi;                 short* w1t_l = wt_lo;
    short* w2t_h = wt_hi + 230400;        short* w2t_l = wt_lo + 230400;
    short* l1t_h = wt_hi + 2390400;       short* l1t_l = wt_lo + 2390400;
    short* l2t_h = wt_hi + 4550400;       short* l2t_l = wt_lo + 4550400;
    short* int_h = wt_hi + 6710400;       short* int_l = wt_lo + 6710400;

    const int* src = eidx;
    const int* dst = eidx + E_EDGES;

    const int QH = H_DIM / 4;
    const dim3 blk(256);
    const dim3 gN  = mfma_grid(N_ATOMS, H_DIM);   // 80*10 = 800
    const dim3 gT  = mfma_grid(M_TAB, H_DIM);     // 16*10 = 160

    // ---- one-time prep (per call)
    init_h_k   <<<(N_ATOMS * QH + 255) / 256, blk, 0, stream>>>(z, emb, h, h_hi, h_lo);
    edge_geom_k<<<(E_EDGES + 255) / 256,      blk, 0, stream>>>(pos, src, dst, einfo);
    rbf_tab_k  <<<(M_TAB * 64 + 255) / 256,   blk, 0, stream>>>(rtab_hi, rtab_lo);
    hipMemsetAsync(deg, 0, 2 * N_ATOMS * sizeof(int), stream);
    hist_k <<<(E_EDGES + 255) / 256, blk, 0, stream>>>(dst, deg);
    scan_k <<<1, 1024, 0, stream>>>(deg, rowptr);
    fill_k <<<(E_EDGES + 255) / 256, blk, 0, stream>>>(dst, einfo, rowptr, cursor, esorted);
    wts_w1_k  <<<dim3(1, 10, 6),  blk, 0, stream>>>(mlp_w1, w1t_h, w1t_l);
    wts_big_k <<<dim3(10, 10, 24), blk, 0, stream>>>(
        mlp_w2, lin1_w, lin2_w, intw,
        w2t_h, w2t_l, l1t_h, l1t_l, l2t_h, l2t_l, int_h, int_l);

    for (int k = 0; k < L_LAYERS; ++k) {
        const float* b1  = mlp_b1 + (size_t)k * H_DIM;
        const float* b2  = mlp_b2 + (size_t)k * H_DIM;
        const float* l2b = lin2_b + (size_t)k * H_DIM;
        const float* ib  = intb   + (size_t)k * H_DIM;
        const short* w1h = w1t_h + (size_t)k * H_DIM * 64;
        const short* w1l = w1t_l + (size_t)k * H_DIM * 64;
        const short* w2h = w2t_h + (size_t)k * H_DIM * H_DIM;
        const short* w2l = w2t_l + (size_t)k * H_DIM * H_DIM;
        const short* l1h = l1t_h + (size_t)k * H_DIM * H_DIM;
        const short* l1l = l1t_l + (size_t)k * H_DIM * H_DIM;
        const short* l2h = l2t_h + (size_t)k * H_DIM * H_DIM;
        const short* l2l = l2t_l + (size_t)k * H_DIM * H_DIM;
        const short* ih  = int_h + (size_t)k * H_DIM * H_DIM;
        const short* il  = int_l + (size_t)k * H_DIM * H_DIM;

        // ttab = ssp(rtab @ w1 + b1)   [2048 x 600], K padded to 64
        gemm_mfma<true, true, false, false, true><<<gT, blk, 0, stream>>>(
            rtab_hi, rtab_lo, 64, w1h, w1l, 64, b1,
            nullptr, ttab_hi, ttab_lo, M_TAB, 64, H_DIM);
        // wtab = ttab @ w2 + b2        [2048 x 600]
        gemm_mfma<true, false, false, true, false><<<gT, blk, 0, stream>>>(
            ttab_hi, ttab_lo, H_DIM, w2h, w2l, H_DIM, b2,
            wtab, nullptr, nullptr, M_TAB, H_DIM, H_DIM);
        // y1 = h @ lin1                [10000 x 600]
        gemm_mfma<false, false, false, true, false><<<gN, blk, 0, stream>>>(
            h_hi, h_lo, H_DIM, l1h, l1l, H_DIM, nullptr,
            y1, nullptr, nullptr, N_ATOMS, H_DIM, H_DIM);
        // agg = CSR-gather(y1 * W(d) * C)  -> bf16 split
        gather_k<<<(N_ATOMS * QH + 255) / 256, blk, 0, stream>>>(
            y1, wtab, rowptr, esorted, agg_hi, agg_lo);
        // t = ssp(agg @ lin2 + b)      -> bf16 split (aliases y1)
        gemm_mfma<true, true, false, false, true><<<gN, blk, 0, stream>>>(
            agg_hi, agg_lo, H_DIM, l2h, l2l, H_DIM, l2b,
            nullptr, t_hi, t_lo, N_ATOMS, H_DIM, H_DIM);
        // h += t @ int_w + ib          (fp32 accumulate + refresh split)
        gemm_mfma<true, false, true, true, true><<<gN, blk, 0, stream>>>(
            t_hi, t_lo, H_DIM, ih, il, H_DIM, ib,
            h, h_hi, h_lo, N_ATOMS, H_DIM, H_DIM);
    }

    // mean pool per molecule, then out = pooled @ pool_w + pool_b
    hipMemsetAsync(sums, 0, (size_t)(B_MOLS * H_DIM + B_MOLS) * sizeof(float), stream);
    pool_sum_k<<<(N_ATOMS * QH + 255) / 256, blk, 0, stream>>>(h, batch, sums);
    cnt_k     <<<(N_ATOMS + 255) / 256,      blk, 0, stream>>>(batch, cnt);
    pool_div_k<<<(B_MOLS * H_DIM + 255) / 256, blk, 0, stream>>>(sums, cnt);
    gemm_k<true><<<dim3((H_DIM + BN - 1) / BN, (B_MOLS + BM - 1) / BM), blk, 0, stream>>>(
        sums, H_DIM, poolw, poolb, (float*)d_out, B_MOLS, H_DIM, H_DIM);
}

// Round 5
// 2106.166 us; speedup vs baseline: 1.5504x; 1.5504x over previous
//
#include <hip/hip_runtime.h>
#include <math.h>

// SchNet forward, MI355X. Round 5: write-amplification fix.
// Round 4 showed WRITE 25->137MB (hbm 181MB = the whole 137us): 600-col rows
// (2400B, not sector-aligned) + scattered 2B bf16-split stores => partial-
// sector RMW. Fix: pad activations to HP=608 cols (2432B = 38*64B sectors),
// pack bf16 hi/lo into ONE int per element (full-sector 4B stores; GEMM
// staging unpacks with 2 shifts/el). K padded to 608 -> no k-guards.
// XCD swizzle + register prefetch (r4), CSR gather (r2), filter table (r1).

#define N_ATOMS 10000
#define E_EDGES 64000
#define B_MOLS  128
#define H_DIM   600
#define HP      608            // padded leading dim (608*4B = 38 sectors)
#define G_DIM   50
#define L_LAYERS 6
#define M_TAB   1024
#define DMAX    8.67f
#define LOG2C   0.69314718056f

#define TM 128
#define TN 64
#define TK 32
#define SA 40          // LDS row stride in shorts

typedef __attribute__((ext_vector_type(8))) short bf16x8;
typedef __attribute__((ext_vector_type(4))) float f32x4;

__device__ __forceinline__ float sspf(float x) {
    return fmaxf(x, 0.0f) + log1pf(expf(-fabsf(x))) - LOG2C;
}
__device__ __forceinline__ short f2bf(float x) {
    unsigned u = __float_as_uint(x);
    unsigned r = (u + 0x7FFF + ((u >> 16) & 1)) >> 16;   // RNE
    return (short)r;
}
__device__ __forceinline__ float bf2f(short h) {
    return __uint_as_float(((unsigned)(unsigned short)h) << 16);
}
// pack fp32 -> (hi bf16 << 16) | lo bf16
__device__ __forceinline__ int packsplit(float x) {
    short hi = f2bf(x);
    short lo = f2bf(x - bf2f(hi));
    return ((int)hi << 16) | ((int)lo & 0xffff);
}
// unpack packed int -> fp32 (exact hi+lo sum)
__device__ __forceinline__ float unpackf(int p) {
    float fh = __uint_as_float((unsigned)p & 0xffff0000u);
    float fl = __uint_as_float(((unsigned)p) << 16);
    return fh + fl;
}

// ---------------------------------------------------------------- MFMA GEMM
// out = op(A @ B + bias). A: packed-split int [Ma][lda] (zero-padded cols).
// B: TRANSPOSED pre-split bf16 hi/lo [Nc][ldb] (zero-padded k). K % 32 == 0,
// no k-guards. Output ldc = HP, pad cols written 0. 1D grid, XCD swizzle.
template<bool BIAS, bool ACT, bool ACCUM, bool WF32, bool WPACK>
__global__ __launch_bounds__(256, 4)
void gemm_mfma(const int* __restrict__ A, int lda,
               const short* __restrict__ Bh, const short* __restrict__ Bl, int ldb,
               const float* __restrict__ bias,
               float* __restrict__ outF, int* __restrict__ outP,
               int Ma, int K, int Nc)
{
    const int NT = (Nc + TN - 1) / TN;
    const int f = blockIdx.x;
    const int xcd = f & 7, s = f >> 3;
    const int n0 = (s % NT) * TN;
    const int m0 = (xcd + 8 * (s / NT)) * TM;
    if (m0 >= Ma) return;

    __shared__ __align__(16) short As[2][TM * SA];   // [hi/lo][m][k]
    __shared__ __align__(16) short Bs[2][TN * SA];   // [hi/lo][n][k]

    const int tid = threadIdx.x;
    const int lane = tid & 63, wid = tid >> 6;
    const int wm = (wid >> 1) * 64, wn = (wid & 1) * 32;
    const int l15 = lane & 15, quad = lane >> 4;

    const int srow = tid >> 3;          // 0..31 (+32*pass)
    const int skk  = (tid & 7) << 2;    // 0,4,..,28

    f32x4 acc[4][2];
    #pragma unroll
    for (int i = 0; i < 4; ++i)
        #pragma unroll
        for (int j = 0; j < 2; ++j)
            acc[i][j] = (f32x4){0.f, 0.f, 0.f, 0.f};

    int4 ra[4];
    short4 rbh[2], rbl[2];

    // prefetch chunk 0
    #pragma unroll
    for (int p = 0; p < 4; ++p) {
        int gm = m0 + p * 32 + srow;
        ra[p] = (gm < Ma) ? *(const int4*)(A + (size_t)gm * lda + skk)
                          : make_int4(0, 0, 0, 0);
    }
    #pragma unroll
    for (int p = 0; p < 2; ++p) {
        int gn = n0 + p * 32 + srow;
        if (gn < Nc) {
            rbh[p] = *(const short4*)(Bh + (size_t)gn * ldb + skk);
            rbl[p] = *(const short4*)(Bl + (size_t)gn * ldb + skk);
        } else { rbh[p] = {0,0,0,0}; rbl[p] = {0,0,0,0}; }
    }

    for (int k0 = 0; k0 < K; k0 += TK) {
        // unpack + store prefetched chunk to LDS
        #pragma unroll
        for (int p = 0; p < 4; ++p) {
            int m = p * 32 + srow;
            int4 v = ra[p];
            short4 vh = { (short)(v.x >> 16), (short)(v.y >> 16),
                          (short)(v.z >> 16), (short)(v.w >> 16) };
            short4 vl = { (short)v.x, (short)v.y, (short)v.z, (short)v.w };
            *(short4*)&As[0][m * SA + skk] = vh;
            *(short4*)&As[1][m * SA + skk] = vl;
        }
        #pragma unroll
        for (int p = 0; p < 2; ++p) {
            int n = p * 32 + srow;
            *(short4*)&Bs[0][n * SA + skk] = rbh[p];
            *(short4*)&Bs[1][n * SA + skk] = rbl[p];
        }
        __syncthreads();

        bf16x8 a_h[4], a_l[4], b_h[2], b_l[2];
        #pragma unroll
        for (int mi = 0; mi < 4; ++mi) {
            int row = wm + mi * 16 + l15;
            a_h[mi] = *(const bf16x8*)&As[0][row * SA + quad * 8];
            a_l[mi] = *(const bf16x8*)&As[1][row * SA + quad * 8];
        }
        #pragma unroll
        for (int ni = 0; ni < 2; ++ni) {
            int col = wn + ni * 16 + l15;
            b_h[ni] = *(const bf16x8*)&Bs[0][col * SA + quad * 8];
            b_l[ni] = *(const bf16x8*)&Bs[1][col * SA + quad * 8];
        }

        // prefetch next chunk (overlaps MFMA)
        int kn = k0 + TK;
        if (kn < K) {
            #pragma unroll
            for (int p = 0; p < 4; ++p) {
                int gm = m0 + p * 32 + srow;
                ra[p] = (gm < Ma) ? *(const int4*)(A + (size_t)gm * lda + kn + skk)
                                  : make_int4(0, 0, 0, 0);
            }
            #pragma unroll
            for (int p = 0; p < 2; ++p) {
                int gn = n0 + p * 32 + srow;
                if (gn < Nc) {
                    rbh[p] = *(const short4*)(Bh + (size_t)gn * ldb + kn + skk);
                    rbl[p] = *(const short4*)(Bl + (size_t)gn * ldb + kn + skk);
                } else { rbh[p] = {0,0,0,0}; rbl[p] = {0,0,0,0}; }
            }
        }

        #pragma unroll
        for (int mi = 0; mi < 4; ++mi)
            #pragma unroll
            for (int ni = 0; ni < 2; ++ni) {
                acc[mi][ni] = __builtin_amdgcn_mfma_f32_16x16x32_bf16(
                    a_h[mi], b_h[ni], acc[mi][ni], 0, 0, 0);
                acc[mi][ni] = __builtin_amdgcn_mfma_f32_16x16x32_bf16(
                    a_h[mi], b_l[ni], acc[mi][ni], 0, 0, 0);
                acc[mi][ni] = __builtin_amdgcn_mfma_f32_16x16x32_bf16(
                    a_l[mi], b_h[ni], acc[mi][ni], 0, 0, 0);
            }
        __syncthreads();
    }

    // epilogue: C/D col = lane&15, row = quad*4 + r. Every 16-lane group
    // stores one full aligned 64B sector (ldc=HP). Pad cols get zeros.
    #pragma unroll
    for (int mi = 0; mi < 4; ++mi) {
        #pragma unroll
        for (int r = 0; r < 4; ++r) {
            int row = m0 + wm + mi * 16 + quad * 4 + r;
            if (row >= Ma) continue;
            #pragma unroll
            for (int ni = 0; ni < 2; ++ni) {
                int col = n0 + wn + ni * 16 + l15;
                if (col >= HP) continue;
                size_t idx = (size_t)row * HP + col;
                float v = 0.0f;
                if (col < Nc) {
                    v = acc[mi][ni][r];
                    if constexpr (BIAS) v += bias[col];
                    if constexpr (ACT)  v = sspf(v);
                    if constexpr (ACCUM) v += outF[idx];
                }
                if constexpr (WF32)  outF[idx] = v;
                if constexpr (WPACK) outP[idx] = packsplit(v);
            }
        }
    }
}

static inline dim3 mfma_grid(int Ma, int Nc) {
    int MB = (Ma + TM - 1) / TM;
    int NT = (Nc + TN - 1) / TN;
    int Ys = ((MB + 7) / 8) * 8;
    return dim3(Ys * NT);
}

// ---------------------------------------------------------------- fp32 GEMM (pool only)
#define BM 64
#define BN 64
#define BK 16
template<bool BIAS>
__global__ __launch_bounds__(256)
void gemm_k(const float* __restrict__ A, int lda,
            const float* __restrict__ W,
            const float* __restrict__ bias,
            float* __restrict__ out,
            int Ma, int K, int Nc)
{
    __shared__ __align__(16) float Asd[BK][BM];
    __shared__ __align__(16) float Bsd[BK][BN];
    const int tid = threadIdx.x;
    const int tx = tid & 15, ty = tid >> 4;
    const int m0 = blockIdx.y * BM, n0 = blockIdx.x * BN;
    const int ar = tid >> 2, ac = (tid & 3) << 2;
    const int br = tid >> 4, bc = (tid & 15) << 2;
    float acc[4][4] = {};
    for (int k0 = 0; k0 < K; k0 += BK) {
        {
            int row = m0 + ar, col = k0 + ac;
            float4 v = make_float4(0.f, 0.f, 0.f, 0.f);
            if (row < Ma) {
                const float* ap = A + (size_t)row * lda + col;
                if (col + 3 < K) v = *(const float4*)ap;
                else {
                    if (col + 0 < K) v.x = ap[0];
                    if (col + 1 < K) v.y = ap[1];
                    if (col + 2 < K) v.z = ap[2];
                }
            }
            Asd[ac + 0][ar] = v.x; Asd[ac + 1][ar] = v.y;
            Asd[ac + 2][ar] = v.z; Asd[ac + 3][ar] = v.w;
        }
        {
            int row = k0 + br, col = n0 + bc;
            float4 v = make_float4(0.f, 0.f, 0.f, 0.f);
            if (row < K && col + 3 < Nc)
                v = *(const float4*)(W + (size_t)row * Nc + col);
            *(float4*)&Bsd[br][bc] = v;
        }
        __syncthreads();
        #pragma unroll
        for (int kk = 0; kk < BK; ++kk) {
            float4 a4 = *(const float4*)&Asd[kk][ty << 2];
            float4 b4 = *(const float4*)&Bsd[kk][tx << 2];
            float av[4] = {a4.x, a4.y, a4.z, a4.w};
            float bv[4] = {b4.x, b4.y, b4.z, b4.w};
            #pragma unroll
            for (int i = 0; i < 4; ++i)
                #pragma unroll
                for (int j = 0; j < 4; ++j)
                    acc[i][j] = fmaf(av[i], bv[j], acc[i][j]);
        }
        __syncthreads();
    }
    #pragma unroll
    for (int i = 0; i < 4; ++i) {
        int row = m0 + (ty << 2) + i;
        if (row >= Ma) continue;
        #pragma unroll
        for (int j = 0; j < 4; ++j) {
            int col = n0 + (tx << 2) + j;
            if (col >= Nc) continue;
            float v = acc[i][j];
            if constexpr (BIAS) v += bias[col];
            out[(size_t)row * Nc + col] = v;
        }
    }
}

// ---------------------------------------------------------------- weight prep
// w1: [50][600] fp32 -> hi/lo [600][64] bf16 (k zero-padded)
__global__ __launch_bounds__(256)
void wts_w1_k(const float* __restrict__ w_all, short* __restrict__ oh,
              short* __restrict__ ol)
{
    __shared__ short th[64][65], tl[64][65];
    const int layer = blockIdx.z;
    const float* w = w_all + (size_t)layer * G_DIM * H_DIM;
    short* ohz = oh + (size_t)layer * H_DIM * 64;
    short* olz = ol + (size_t)layer * H_DIM * 64;
    const int n0 = blockIdx.y * 64;
    const int tid = threadIdx.x;
    #pragma unroll
    for (int p = 0; p < 4; ++p) {
        int k = p * 16 + (tid >> 4);
        int n4 = (tid & 15) << 2;
        float4 v = make_float4(0.f, 0.f, 0.f, 0.f);
        if (k < G_DIM && n0 + n4 + 3 < H_DIM)
            v = *(const float4*)(w + (size_t)k * H_DIM + n0 + n4);
        int px = packsplit(v.x), py = packsplit(v.y);
        int pz = packsplit(v.z), pw = packsplit(v.w);
        th[n4 + 0][k] = (short)(px >> 16); tl[n4 + 0][k] = (short)px;
        th[n4 + 1][k] = (short)(py >> 16); tl[n4 + 1][k] = (short)py;
        th[n4 + 2][k] = (short)(pz >> 16); tl[n4 + 2][k] = (short)pz;
        th[n4 + 3][k] = (short)(pw >> 16); tl[n4 + 3][k] = (short)pw;
    }
    __syncthreads();
    #pragma unroll
    for (int p = 0; p < 4; ++p) {
        int n = p * 16 + (tid >> 4);
        int k4 = (tid & 15) << 2;
        if (n0 + n >= H_DIM) continue;
        short4 sh = { th[n][k4], th[n][k4 + 1], th[n][k4 + 2], th[n][k4 + 3] };
        short4 sl = { tl[n][k4], tl[n][k4 + 1], tl[n][k4 + 2], tl[n][k4 + 3] };
        *(short4*)(ohz + (size_t)(n0 + n) * 64 + k4) = sh;
        *(short4*)(olz + (size_t)(n0 + n) * 64 + k4) = sl;
    }
}

// big weights [600][600] -> hi/lo [600][HP] (k zero-padded 600..607)
__global__ __launch_bounds__(256)
void wts_big_k(const float* __restrict__ w2, const float* __restrict__ l1,
               const float* __restrict__ l2, const float* __restrict__ iw,
               short* __restrict__ oh2, short* __restrict__ ol2,
               short* __restrict__ oh1, short* __restrict__ ol1,
               short* __restrict__ ohl2, short* __restrict__ oll2,
               short* __restrict__ ohi, short* __restrict__ oli)
{
    __shared__ short th[64][65], tl[64][65];
    const int z = blockIdx.z, type = z / L_LAYERS, layer = z % L_LAYERS;
    const float* w; short* oh; short* ol;
    if (type == 0)      { w = w2; oh = oh2; ol = ol2; }
    else if (type == 1) { w = l1; oh = oh1; ol = ol1; }
    else if (type == 2) { w = l2; oh = ohl2; ol = oll2; }
    else                { w = iw; oh = ohi; ol = oli; }
    w  += (size_t)layer * H_DIM * H_DIM;
    oh += (size_t)layer * H_DIM * HP;
    ol += (size_t)layer * H_DIM * HP;
    const int k0 = blockIdx.x * 64, n0 = blockIdx.y * 64;
    const int tid = threadIdx.x;
    #pragma unroll
    for (int p = 0; p < 4; ++p) {
        int k = p * 16 + (tid >> 4);
        int n4 = (tid & 15) << 2;
        float4 v = make_float4(0.f, 0.f, 0.f, 0.f);
        if (k0 + k < H_DIM && n0 + n4 + 3 < H_DIM)
            v = *(const float4*)(w + (size_t)(k0 + k) * H_DIM + n0 + n4);
        int px = packsplit(v.x), py = packsplit(v.y);
        int pz = packsplit(v.z), pw = packsplit(v.w);
        th[n4 + 0][k] = (short)(px >> 16); tl[n4 + 0][k] = (short)px;
        th[n4 + 1][k] = (short)(py >> 16); tl[n4 + 1][k] = (short)py;
        th[n4 + 2][k] = (short)(pz >> 16); tl[n4 + 2][k] = (short)pz;
        th[n4 + 3][k] = (short)(pw >> 16); tl[n4 + 3][k] = (short)pw;
    }
    __syncthreads();
    #pragma unroll
    for (int p = 0; p < 4; ++p) {
        int n = p * 16 + (tid >> 4);
        int k4 = (tid & 15) << 2;
        if (n0 + n >= H_DIM || k0 + k4 > HP - 4) continue;
        short4 sh = { th[n][k4], th[n][k4 + 1], th[n][k4 + 2], th[n][k4 + 3] };
        short4 sl = { tl[n][k4], tl[n][k4 + 1], tl[n][k4 + 2], tl[n][k4 + 3] };
        *(short4*)(oh + (size_t)(n0 + n) * HP + k0 + k4) = sh;
        *(short4*)(ol + (size_t)(n0 + n) * HP + k0 + k4) = sl;
    }
}

// ---------------------------------------------------------------- helpers
__global__ __launch_bounds__(256)
void init_h_k(const int* __restrict__ z, const float* __restrict__ emb,
              float* __restrict__ h, int* __restrict__ hP)
{
    int t = blockIdx.x * 256 + threadIdx.x;
    const int QC = HP / 4;   // 152
    if (t >= N_ATOMS * QC) return;
    int i = t / QC;
    int q = (t - i * QC) << 2;
    size_t idx = (size_t)i * HP + q;
    if (q < H_DIM) {
        float4 v = *(const float4*)(emb + (size_t)z[i] * H_DIM + q);
        *(float4*)(h + idx) = v;
        *(int4*)(hP + idx) = make_int4(packsplit(v.x), packsplit(v.y),
                                       packsplit(v.z), packsplit(v.w));
    } else {
        *(float4*)(h + idx) = make_float4(0.f, 0.f, 0.f, 0.f);
        *(int4*)(hP + idx) = make_int4(0, 0, 0, 0);
    }
}

// per-edge record: {src*HP, i0*HP, a = C - f*C, b = f*C}; contribution =
// y * (a*w0 + b*w1)
__global__ __launch_bounds__(256)
void edge_geom_k(const float* __restrict__ pos, const int* __restrict__ src,
                 const int* __restrict__ dst, float4* __restrict__ einfo)
{
    int e = blockIdx.x * 256 + threadIdx.x;
    if (e >= E_EDGES) return;
    int s = src[e], d0 = dst[e];
    float dx = pos[s * 3 + 0] - pos[d0 * 3 + 0];
    float dy = pos[s * 3 + 1] - pos[d0 * 3 + 1];
    float dz = pos[s * 3 + 2] - pos[d0 * 3 + 2];
    float dist = sqrtf(dx * dx + dy * dy + dz * dz + 1e-12f);
    float cc = 0.5f * (cosf(dist * 0.31415926535f) + 1.0f);
    float u = dist * ((float)(M_TAB - 1) / DMAX);
    u = fminf(fmaxf(u, 0.0f), (float)(M_TAB - 1) - 0.001f);
    int i0 = (int)u;
    float fc = (u - (float)i0) * cc;
    einfo[e] = make_float4(__int_as_float(s * HP),
                           __int_as_float(i0 * HP),
                           cc - fc, fc);
}

// rbf table [M_TAB][64] packed, zero for g >= 50
__global__ __launch_bounds__(256)
void rbf_tab_k(int* __restrict__ rtabP)
{
    int t = blockIdx.x * 256 + threadIdx.x;
    if (t >= M_TAB * 64) return;
    int i = t >> 6, g = t & 63;
    float v = 0.0f;
    if (g < G_DIM) {
        float dg  = (float)i * (DMAX / (float)(M_TAB - 1));
        float off = (float)g * (10.0f / 49.0f);
        float x = dg - off;
        const float coeff = -0.5f * (49.0f / 10.0f) * (49.0f / 10.0f);
        v = expf(coeff * x * x);
    }
    rtabP[t] = packsplit(v);
}

// ---------------------------------------------------------------- CSR build
__global__ __launch_bounds__(256)
void hist_k(const int* __restrict__ dst, int* __restrict__ deg)
{
    int e = blockIdx.x * 256 + threadIdx.x;
    if (e >= E_EDGES) return;
    atomicAdd(&deg[dst[e]], 1);
}

__global__ __launch_bounds__(1024)
void scan_k(const int* __restrict__ deg, int* __restrict__ rowptr)
{
    __shared__ int sums[1024];
    int tid = threadIdx.x;
    const int CHUNK = (N_ATOMS + 1023) / 1024;
    int base = tid * CHUNK;
    int local[16];
    int s = 0;
    #pragma unroll
    for (int c = 0; c < 16; ++c) {
        if (c >= CHUNK) break;
        int idx = base + c;
        local[c] = s;
        s += (idx < N_ATOMS) ? deg[idx] : 0;
    }
    sums[tid] = s;
    __syncthreads();
    for (int off = 1; off < 1024; off <<= 1) {
        int v = (tid >= off) ? sums[tid - off] : 0;
        __syncthreads();
        sums[tid] += v;
        __syncthreads();
    }
    int prefix = (tid > 0) ? sums[tid - 1] : 0;
    #pragma unroll
    for (int c = 0; c < 16; ++c) {
        if (c >= CHUNK) break;
        int idx = base + c;
        if (idx <= N_ATOMS) rowptr[idx] = prefix + local[c];
    }
    if (tid == 1023) rowptr[N_ATOMS] = sums[1023];
}

__global__ __launch_bounds__(256)
void fill_k(const int* __restrict__ dst, const float4* __restrict__ einfo,
            const int* __restrict__ rowptr, int* __restrict__ cursor,
            float4* __restrict__ esorted)
{
    int e = blockIdx.x * 256 + threadIdx.x;
    if (e >= E_EDGES) return;
    int d0 = dst[e];
    int pos = rowptr[d0] + atomicAdd(&cursor[d0], 1);
    esorted[pos] = einfo[e];
}

// ---------------------------------------------------------------- gather
// aggP[i][q..] = packsplit( sum_e y[src] * (a*w0 + b*w1) ); y/wtab packed.
__global__ __launch_bounds__(256)
void gather_k(const int* __restrict__ yP, const int* __restrict__ wtP,
              const int* __restrict__ rowptr, const float4* __restrict__ esorted,
              int* __restrict__ aggP)
{
    int t = blockIdx.x * 256 + threadIdx.x;
    const int QC = HP / 4;   // 152
    if (t >= N_ATOMS * QC) return;
    int i = t / QC;
    int q = (t - i * QC) << 2;
    size_t idx = (size_t)i * HP + q;
    if (q >= H_DIM) { *(int4*)(aggP + idx) = make_int4(0, 0, 0, 0); return; }
    int j0 = rowptr[i], j1 = rowptr[i + 1];
    float4 acc = make_float4(0.f, 0.f, 0.f, 0.f);
    for (int j = j0; j < j1; ++j) {
        float4 ei = esorted[j];
        int srow = __float_as_int(ei.x);
        int wrow = __float_as_int(ei.y);
        float a = ei.z, b = ei.w;
        int4 yv = *(const int4*)(yP + srow + q);
        int4 w0 = *(const int4*)(wtP + wrow + q);
        int4 w1 = *(const int4*)(wtP + wrow + HP + q);
        acc.x += unpackf(yv.x) * (a * unpackf(w0.x) + b * unpackf(w1.x));
        acc.y += unpackf(yv.y) * (a * unpackf(w0.y) + b * unpackf(w1.y));
        acc.z += unpackf(yv.z) * (a * unpackf(w0.z) + b * unpackf(w1.z));
        acc.w += unpackf(yv.w) * (a * unpackf(w0.w) + b * unpackf(w1.w));
    }
    *(int4*)(aggP + idx) = make_int4(packsplit(acc.x), packsplit(acc.y),
                                     packsplit(acc.z), packsplit(acc.w));
}

// ---------------------------------------------------------------- pool
__global__ __launch_bounds__(256)
void pool_sum_k(const float* __restrict__ h, const int* __restrict__ batch,
                float* __restrict__ sums)
{
    int t = blockIdx.x * 256 + threadIdx.x;
    const int QH = H_DIM / 4;   // 150
    if (t >= N_ATOMS * QH) return;
    int i = t / QH;
    int q = (t - i * QH) << 2;
    int b = batch[i];
    const float4 hv = *(const float4*)(h + (size_t)i * HP + q);
    float* sp = sums + (size_t)b * H_DIM + q;
    atomicAdd(sp + 0, hv.x);
    atomicAdd(sp + 1, hv.y);
    atomicAdd(sp + 2, hv.z);
    atomicAdd(sp + 3, hv.w);
}

__global__ __launch_bounds__(256)
void cnt_k(const int* __restrict__ batch, float* __restrict__ cnt)
{
    int i = blockIdx.x * 256 + threadIdx.x;
    if (i >= N_ATOMS) return;
    atomicAdd(&cnt[batch[i]], 1.0f);
}

__global__ __launch_bounds__(256)
void pool_div_k(float* __restrict__ sums, const float* __restrict__ cnt)
{
    int t = blockIdx.x * 256 + threadIdx.x;
    if (t >= B_MOLS * H_DIM) return;
    sums[t] /= fmaxf(cnt[t / H_DIM], 1.0f);
}

// ---------------------------------------------------------------- launch
extern "C" void kernel_launch(void* const* d_in, const int* in_sizes, int n_in,
                              void* d_out, int out_size, void* d_ws, size_t ws_size,
                              hipStream_t stream)
{
    const int*   z      = (const int*)  d_in[0];
    const float* pos    = (const float*)d_in[1];
    const int*   batch  = (const int*)  d_in[2];
    const int*   eidx   = (const int*)  d_in[3];
    const float* emb    = (const float*)d_in[4];
    const float* mlp_w1 = (const float*)d_in[5];
    const float* mlp_b1 = (const float*)d_in[6];
    const float* mlp_w2 = (const float*)d_in[7];
    const float* mlp_b2 = (const float*)d_in[8];
    const float* lin1_w = (const float*)d_in[9];
    const float* lin2_w = (const float*)d_in[10];
    const float* lin2_b = (const float*)d_in[11];
    const float* intw   = (const float*)d_in[12];
    const float* intb   = (const float*)d_in[13];
    const float* poolw  = (const float*)d_in[14];
    const float* poolb  = (const float*)d_in[15];

    float* ws = (float*)d_ws;
    const size_t NHP = (size_t)N_ATOMS * HP;       // 6,080,000
    const size_t THP = (size_t)M_TAB * HP;         // 622,592
    float* h     = ws;                             // fp32 master
    int*   hP    = (int*)(ws + NHP);               // packed split
    int*   y1P   = (int*)(ws + 2 * NHP);           // packed; aliases tP
    int*   tP    = y1P;
    int*   aggP  = (int*)(ws + 3 * NHP);
    // aggP region aliases (dead at those phases):
    float4* einfo  = (float4*)aggP;                          // 256,000 f
    int*    deg    = (int*)((float*)aggP + 300000);          // 10,000
    int*    cursor = (int*)((float*)aggP + 310000);          // 10,000
    float*  sums   = (float*)aggP + 320000;                  // 76,800
    float*  cnt    = (float*)aggP + 396800;                  // 128
    int*   ttabP = (int*)(ws + 4 * NHP);           // 622,592
    int*   wtabP = (int*)(ws + 4 * NHP + THP);     // 622,592
    int*   rtabP = (int*)(ws + 4 * NHP + 2 * THP); // M_TAB*64 = 65,536
    short* wtH   = (short*)(ws + 4 * NHP + 2 * THP + (size_t)M_TAB * 64);
    // wtH/wtL: 6*600*64 + 4*6*600*608 = 8,985,600 shorts = 4,492,800 f each
    short* wtL   = wtH + 8985600;
    float* after = (float*)(wtH) + 8985600;        // = base + 8,985,600 floats... (shorts!)
    float4* esorted = (float4*)((float*)(wtL + 8985600));    // 256,000 f
    int*    rowptr  = (int*)((float*)esorted + 256000);      // 10,001
    (void)after;
    // end ~= 4*6,080,000 + 2*622,592 + 65,536 + 8,985,600(=4,492,800f*2)
    //        + 256,000 + 10,001 ~= 35.5M floats = 142.0 MB

    short* w1t_h = wtH;                       short* w1t_l = wtL;
    short* w2t_h = wtH + 230400;              short* w2t_l = wtL + 230400;
    short* l1t_h = w2t_h + 6 * 600 * HP;      short* l1t_l = w2t_l + 6 * 600 * HP;
    short* l2t_h = l1t_h + 6 * 600 * HP;      short* l2t_l = l1t_l + 6 * 600 * HP;
    short* int_h = l2t_h + 6 * 600 * HP;      short* int_l = l2t_l + 6 * 600 * HP;

    const int* src = eidx;
    const int* dst = eidx + E_EDGES;

    const dim3 blk(256);
    const int QC = HP / 4;
    const dim3 gN = mfma_grid(N_ATOMS, H_DIM);   // 80*10 = 800
    const dim3 gT = mfma_grid(M_TAB, H_DIM);     // 8*10  = 80

    // ---- one-time prep (einfo/deg/cursor alias aggP: all dead before gather)
    edge_geom_k<<<(E_EDGES + 255) / 256, blk, 0, stream>>>(pos, src, dst, einfo);
    hipMemsetAsync(deg, 0, 2 * N_ATOMS * sizeof(int), stream);
    hist_k <<<(E_EDGES + 255) / 256, blk, 0, stream>>>(dst, deg);
    scan_k <<<1, 1024, 0, stream>>>(deg, rowptr);
    fill_k <<<(E_EDGES + 255) / 256, blk, 0, stream>>>(dst, einfo, rowptr, cursor, esorted);
    init_h_k <<<(N_ATOMS * QC + 255) / 256, blk, 0, stream>>>(z, emb, h, hP);
    rbf_tab_k<<<(M_TAB * 64 + 255) / 256,   blk, 0, stream>>>(rtabP);
    wts_w1_k  <<<dim3(1, 10, 6),   blk, 0, stream>>>(mlp_w1, w1t_h, w1t_l);
    wts_big_k <<<dim3(10, 10, 24), blk, 0, stream>>>(
        mlp_w2, lin1_w, lin2_w, intw,
        w2t_h, w2t_l, l1t_h, l1t_l, l2t_h, l2t_l, int_h, int_l);

    for (int k = 0; k < L_LAYERS; ++k) {
        const float* b1  = mlp_b1 + (size_t)k * H_DIM;
        const float* b2  = mlp_b2 + (size_t)k * H_DIM;
        const float* l2b = lin2_b + (size_t)k * H_DIM;
        const float* ib  = intb   + (size_t)k * H_DIM;
        const short* w1h = w1t_h + (size_t)k * H_DIM * 64;
        const short* w1l = w1t_l + (size_t)k * H_DIM * 64;
        const short* w2h = w2t_h + (size_t)k * H_DIM * HP;
        const short* w2l = w2t_l + (size_t)k * H_DIM * HP;
        const short* l1h = l1t_h + (size_t)k * H_DIM * HP;
        const short* l1l = l1t_l + (size_t)k * H_DIM * HP;
        const short* l2h = l2t_h + (size_t)k * H_DIM * HP;
        const short* l2l = l2t_l + (size_t)k * H_DIM * HP;
        const short* ih  = int_h + (size_t)k * H_DIM * HP;
        const short* il  = int_l + (size_t)k * H_DIM * HP;

        // ttabP = packsplit(ssp(rtab @ w1 + b1))   [M_TAB x 600], K=64
        gemm_mfma<true, true, false, false, true><<<gT, blk, 0, stream>>>(
            rtabP, 64, w1h, w1l, 64, b1,
            nullptr, ttabP, M_TAB, 64, H_DIM);
        // wtabP = packsplit(ttab @ w2 + b2)        [M_TAB x 600], K=HP
        gemm_mfma<true, false, false, false, true><<<gT, blk, 0, stream>>>(
            ttabP, HP, w2h, w2l, HP, b2,
            nullptr, wtabP, M_TAB, HP, H_DIM);
        // y1P = packsplit(h @ lin1)                [N x 600]
        gemm_mfma<false, false, false, false, true><<<gN, blk, 0, stream>>>(
            hP, HP, l1h, l1l, HP, nullptr,
            nullptr, y1P, N_ATOMS, HP, H_DIM);
        // aggP = packsplit(CSR-gather(y1 * W(d) * C))
        gather_k<<<(N_ATOMS * QC + 255) / 256, blk, 0, stream>>>(
            y1P, wtabP, rowptr, esorted, aggP);
        // tP = packsplit(ssp(agg @ lin2 + b))      (aliases y1P)
        gemm_mfma<true, true, false, false, true><<<gN, blk, 0, stream>>>(
            aggP, HP, l2h, l2l, HP, l2b,
            nullptr, tP, N_ATOMS, HP, H_DIM);
        // h += t @ int_w + ib  (fp32 master + refresh packed split)
        gemm_mfma<true, false, true, true, true><<<gN, blk, 0, stream>>>(
            tP, HP, ih, il, HP, ib,
            h, hP, N_ATOMS, HP, H_DIM);
    }

    // mean pool per molecule, then out = pooled @ pool_w + pool_b
    // (sums/cnt alias aggP region — aggP dead after last l2 GEMM)
    hipMemsetAsync(sums, 0, (size_t)(B_MOLS * H_DIM + B_MOLS) * sizeof(float), stream);
    pool_sum_k<<<(N_ATOMS * (H_DIM / 4) + 255) / 256, blk, 0, stream>>>(h, batch, sums);
    cnt_k     <<<(N_ATOMS + 255) / 256,      blk, 0, stream>>>(batch, cnt);
    pool_div_k<<<(B_MOLS * H_DIM + 255) / 256, blk, 0, stream>>>(sums, cnt);
    gemm_k<true><<<dim3((H_DIM + BN - 1) / BN, (B_MOLS + BM - 1) / BM), blk, 0, stream>>>(
        sums, H_DIM, poolw, poolb, (float*)d_out, B_MOLS, H_DIM, H_DIM);
}

// Round 6
// 1556.337 us; speedup vs baseline: 2.0981x; 1.3533x over previous
//
#include <hip/hip_runtime.h>
#include <math.h>

// SchNet forward, MI355X. Round 6: occupancy fix for the latency-bound GEMM.
// Round 5: all pipes <=32% (Mfma 9%, VALU 32%, HBM 7%), Occupancy 30% —
// 790 blocks/256 CUs with lockstep barriers = latency plateau (m102 curve).
// Fix: 64x64 tiles -> 1570 blocks (~6/CU), 20KB LDS, launch_bounds(256,6),
// prefetch issued before fragment ds_reads. Packed hi/lo int format +
// sector-aligned HP=608 (r5), XCD swizzle (r4), CSR gather (r2), table (r1).

#define N_ATOMS 10000
#define E_EDGES 64000
#define B_MOLS  128
#define H_DIM   600
#define HP      608            // padded leading dim (608*4B = 38 sectors)
#define G_DIM   50
#define L_LAYERS 6
#define M_TAB   1024
#define DMAX    8.67f
#define LOG2C   0.69314718056f

#define TM 64
#define TN 64
#define TK 32
#define SA 40          // LDS row stride in shorts (80B rows)

typedef __attribute__((ext_vector_type(8))) short bf16x8;
typedef __attribute__((ext_vector_type(4))) float f32x4;

__device__ __forceinline__ float sspf(float x) {
    return fmaxf(x, 0.0f) + log1pf(expf(-fabsf(x))) - LOG2C;
}
__device__ __forceinline__ short f2bf(float x) {
    unsigned u = __float_as_uint(x);
    unsigned r = (u + 0x7FFF + ((u >> 16) & 1)) >> 16;   // RNE
    return (short)r;
}
__device__ __forceinline__ float bf2f(short h) {
    return __uint_as_float(((unsigned)(unsigned short)h) << 16);
}
// pack fp32 -> (hi bf16 << 16) | lo bf16
__device__ __forceinline__ int packsplit(float x) {
    short hi = f2bf(x);
    short lo = f2bf(x - bf2f(hi));
    return ((int)hi << 16) | ((int)lo & 0xffff);
}
// unpack packed int -> fp32 (exact hi+lo sum)
__device__ __forceinline__ float unpackf(int p) {
    float fh = __uint_as_float((unsigned)p & 0xffff0000u);
    float fl = __uint_as_float(((unsigned)p) << 16);
    return fh + fl;
}

// ---------------------------------------------------------------- MFMA GEMM
// out = op(A @ B + bias). A: packed-split int [Ma][lda] (zero-padded cols).
// B: TRANSPOSED pre-split bf16 hi/lo [Nc][ldb] (zero-padded k). K % 32 == 0.
// Output ldc = HP, pad cols written 0. 1D grid, XCD swizzle.
template<bool BIAS, bool ACT, bool ACCUM, bool WF32, bool WPACK>
__global__ __launch_bounds__(256, 6)
void gemm_mfma(const int* __restrict__ A, int lda,
               const short* __restrict__ Bh, const short* __restrict__ Bl, int ldb,
               const float* __restrict__ bias,
               float* __restrict__ outF, int* __restrict__ outP,
               int Ma, int K, int Nc)
{
    const int NT = (Nc + TN - 1) / TN;
    const int f = blockIdx.x;
    const int xcd = f & 7, s = f >> 3;
    const int n0 = (s % NT) * TN;
    const int m0 = (xcd + 8 * (s / NT)) * TM;
    if (m0 >= Ma) return;

    __shared__ __align__(16) short As[2][TM * SA];   // [hi/lo][m][k]
    __shared__ __align__(16) short Bs[2][TN * SA];   // [hi/lo][n][k]

    const int tid = threadIdx.x;
    const int lane = tid & 63, wid = tid >> 6;
    const int wm = (wid >> 1) * 32, wn = (wid & 1) * 32;
    const int l15 = lane & 15, quad = lane >> 4;

    // staging map: 64 rows x 32 k; thread -> row tid>>2, k-octet (tid&3)*8
    const int srow = tid >> 2;          // 0..63
    const int skk  = (tid & 3) << 3;    // 0,8,16,24

    f32x4 acc[2][2];
    #pragma unroll
    for (int i = 0; i < 2; ++i)
        #pragma unroll
        for (int j = 0; j < 2; ++j)
            acc[i][j] = (f32x4){0.f, 0.f, 0.f, 0.f};

    int4 ra0, ra1;
    short4 rbh0, rbh1, rbl0, rbl1;

    // prefetch chunk 0
    {
        int gm = m0 + srow;
        if (gm < Ma) {
            const int* ap = A + (size_t)gm * lda + skk;
            ra0 = *(const int4*)ap; ra1 = *(const int4*)(ap + 4);
        } else { ra0 = make_int4(0,0,0,0); ra1 = make_int4(0,0,0,0); }
        int gn = n0 + srow;
        if (gn < Nc) {
            const short* bp = Bh + (size_t)gn * ldb + skk;
            const short* lp = Bl + (size_t)gn * ldb + skk;
            rbh0 = *(const short4*)bp; rbh1 = *(const short4*)(bp + 4);
            rbl0 = *(const short4*)lp; rbl1 = *(const short4*)(lp + 4);
        } else { rbh0 = {0,0,0,0}; rbh1 = {0,0,0,0};
                 rbl0 = {0,0,0,0}; rbl1 = {0,0,0,0}; }
    }

    for (int k0 = 0; k0 < K; k0 += TK) {
        // unpack + store prefetched chunk to LDS
        {
            short4 vh0 = { (short)(ra0.x >> 16), (short)(ra0.y >> 16),
                           (short)(ra0.z >> 16), (short)(ra0.w >> 16) };
            short4 vl0 = { (short)ra0.x, (short)ra0.y, (short)ra0.z, (short)ra0.w };
            short4 vh1 = { (short)(ra1.x >> 16), (short)(ra1.y >> 16),
                           (short)(ra1.z >> 16), (short)(ra1.w >> 16) };
            short4 vl1 = { (short)ra1.x, (short)ra1.y, (short)ra1.z, (short)ra1.w };
            *(short4*)&As[0][srow * SA + skk]     = vh0;
            *(short4*)&As[0][srow * SA + skk + 4] = vh1;
            *(short4*)&As[1][srow * SA + skk]     = vl0;
            *(short4*)&As[1][srow * SA + skk + 4] = vl1;
            *(short4*)&Bs[0][srow * SA + skk]     = rbh0;
            *(short4*)&Bs[0][srow * SA + skk + 4] = rbh1;
            *(short4*)&Bs[1][srow * SA + skk]     = rbl0;
            *(short4*)&Bs[1][srow * SA + skk + 4] = rbl1;
        }
        __syncthreads();

        // issue next-chunk global prefetch FIRST (in flight through MFMAs)
        int kn = k0 + TK;
        if (kn < K) {
            int gm = m0 + srow;
            if (gm < Ma) {
                const int* ap = A + (size_t)gm * lda + kn + skk;
                ra0 = *(const int4*)ap; ra1 = *(const int4*)(ap + 4);
            } else { ra0 = make_int4(0,0,0,0); ra1 = make_int4(0,0,0,0); }
            int gn = n0 + srow;
            if (gn < Nc) {
                const short* bp = Bh + (size_t)gn * ldb + kn + skk;
                const short* lp = Bl + (size_t)gn * ldb + kn + skk;
                rbh0 = *(const short4*)bp; rbh1 = *(const short4*)(bp + 4);
                rbl0 = *(const short4*)lp; rbl1 = *(const short4*)(lp + 4);
            } else { rbh0 = {0,0,0,0}; rbh1 = {0,0,0,0};
                     rbl0 = {0,0,0,0}; rbl1 = {0,0,0,0}; }
        }

        bf16x8 a_h[2], a_l[2], b_h[2], b_l[2];
        #pragma unroll
        for (int mi = 0; mi < 2; ++mi) {
            int row = wm + mi * 16 + l15;
            a_h[mi] = *(const bf16x8*)&As[0][row * SA + quad * 8];
            a_l[mi] = *(const bf16x8*)&As[1][row * SA + quad * 8];
        }
        #pragma unroll
        for (int ni = 0; ni < 2; ++ni) {
            int col = wn + ni * 16 + l15;
            b_h[ni] = *(const bf16x8*)&Bs[0][col * SA + quad * 8];
            b_l[ni] = *(const bf16x8*)&Bs[1][col * SA + quad * 8];
        }

        #pragma unroll
        for (int mi = 0; mi < 2; ++mi)
            #pragma unroll
            for (int ni = 0; ni < 2; ++ni) {
                acc[mi][ni] = __builtin_amdgcn_mfma_f32_16x16x32_bf16(
                    a_h[mi], b_h[ni], acc[mi][ni], 0, 0, 0);
                acc[mi][ni] = __builtin_amdgcn_mfma_f32_16x16x32_bf16(
                    a_h[mi], b_l[ni], acc[mi][ni], 0, 0, 0);
                acc[mi][ni] = __builtin_amdgcn_mfma_f32_16x16x32_bf16(
                    a_l[mi], b_h[ni], acc[mi][ni], 0, 0, 0);
            }
        __syncthreads();
    }

    // epilogue: C/D col = lane&15, row = quad*4 + r; 16-lane groups store
    // full aligned 64B sectors (ldc=HP). Pad cols get zeros.
    #pragma unroll
    for (int mi = 0; mi < 2; ++mi) {
        #pragma unroll
        for (int r = 0; r < 4; ++r) {
            int row = m0 + wm + mi * 16 + quad * 4 + r;
            if (row >= Ma) continue;
            #pragma unroll
            for (int ni = 0; ni < 2; ++ni) {
                int col = n0 + wn + ni * 16 + l15;
                if (col >= HP) continue;
                size_t idx = (size_t)row * HP + col;
                float v = 0.0f;
                if (col < Nc) {
                    v = acc[mi][ni][r];
                    if constexpr (BIAS) v += bias[col];
                    if constexpr (ACT)  v = sspf(v);
                    if constexpr (ACCUM) v += outF[idx];
                }
                if constexpr (WF32)  outF[idx] = v;
                if constexpr (WPACK) outP[idx] = packsplit(v);
            }
        }
    }
}

static inline dim3 mfma_grid(int Ma, int Nc) {
    int MB = (Ma + TM - 1) / TM;
    int NT = (Nc + TN - 1) / TN;
    int Ys = ((MB + 7) / 8) * 8;
    return dim3(Ys * NT);
}

// ---------------------------------------------------------------- fp32 GEMM (pool only)
#define BM 64
#define BN 64
#define BK 16
template<bool BIAS>
__global__ __launch_bounds__(256)
void gemm_k(const float* __restrict__ A, int lda,
            const float* __restrict__ W,
            const float* __restrict__ bias,
            float* __restrict__ out,
            int Ma, int K, int Nc)
{
    __shared__ __align__(16) float Asd[BK][BM];
    __shared__ __align__(16) float Bsd[BK][BN];
    const int tid = threadIdx.x;
    const int tx = tid & 15, ty = tid >> 4;
    const int m0 = blockIdx.y * BM, n0 = blockIdx.x * BN;
    const int ar = tid >> 2, ac = (tid & 3) << 2;
    const int br = tid >> 4, bc = (tid & 15) << 2;
    float acc[4][4] = {};
    for (int k0 = 0; k0 < K; k0 += BK) {
        {
            int row = m0 + ar, col = k0 + ac;
            float4 v = make_float4(0.f, 0.f, 0.f, 0.f);
            if (row < Ma) {
                const float* ap = A + (size_t)row * lda + col;
                if (col + 3 < K) v = *(const float4*)ap;
                else {
                    if (col + 0 < K) v.x = ap[0];
                    if (col + 1 < K) v.y = ap[1];
                    if (col + 2 < K) v.z = ap[2];
                }
            }
            Asd[ac + 0][ar] = v.x; Asd[ac + 1][ar] = v.y;
            Asd[ac + 2][ar] = v.z; Asd[ac + 3][ar] = v.w;
        }
        {
            int row = k0 + br, col = n0 + bc;
            float4 v = make_float4(0.f, 0.f, 0.f, 0.f);
            if (row < K && col + 3 < Nc)
                v = *(const float4*)(W + (size_t)row * Nc + col);
            *(float4*)&Bsd[br][bc] = v;
        }
        __syncthreads();
        #pragma unroll
        for (int kk = 0; kk < BK; ++kk) {
            float4 a4 = *(const float4*)&Asd[kk][ty << 2];
            float4 b4 = *(const float4*)&Bsd[kk][tx << 2];
            float av[4] = {a4.x, a4.y, a4.z, a4.w};
            float bv[4] = {b4.x, b4.y, b4.z, b4.w};
            #pragma unroll
            for (int i = 0; i < 4; ++i)
                #pragma unroll
                for (int j = 0; j < 4; ++j)
                    acc[i][j] = fmaf(av[i], bv[j], acc[i][j]);
        }
        __syncthreads();
    }
    #pragma unroll
    for (int i = 0; i < 4; ++i) {
        int row = m0 + (ty << 2) + i;
        if (row >= Ma) continue;
        #pragma unroll
        for (int j = 0; j < 4; ++j) {
            int col = n0 + (tx << 2) + j;
            if (col >= Nc) continue;
            float v = acc[i][j];
            if constexpr (BIAS) v += bias[col];
            out[(size_t)row * Nc + col] = v;
        }
    }
}

// ---------------------------------------------------------------- weight prep
// w1: [50][600] fp32 -> hi/lo [600][64] bf16 (k zero-padded)
__global__ __launch_bounds__(256)
void wts_w1_k(const float* __restrict__ w_all, short* __restrict__ oh,
              short* __restrict__ ol)
{
    __shared__ short th[64][65], tl[64][65];
    const int layer = blockIdx.z;
    const float* w = w_all + (size_t)layer * G_DIM * H_DIM;
    short* ohz = oh + (size_t)layer * H_DIM * 64;
    short* olz = ol + (size_t)layer * H_DIM * 64;
    const int n0 = blockIdx.y * 64;
    const int tid = threadIdx.x;
    #pragma unroll
    for (int p = 0; p < 4; ++p) {
        int k = p * 16 + (tid >> 4);
        int n4 = (tid & 15) << 2;
        float4 v = make_float4(0.f, 0.f, 0.f, 0.f);
        if (k < G_DIM && n0 + n4 + 3 < H_DIM)
            v = *(const float4*)(w + (size_t)k * H_DIM + n0 + n4);
        int px = packsplit(v.x), py = packsplit(v.y);
        int pz = packsplit(v.z), pw = packsplit(v.w);
        th[n4 + 0][k] = (short)(px >> 16); tl[n4 + 0][k] = (short)px;
        th[n4 + 1][k] = (short)(py >> 16); tl[n4 + 1][k] = (short)py;
        th[n4 + 2][k] = (short)(pz >> 16); tl[n4 + 2][k] = (short)pz;
        th[n4 + 3][k] = (short)(pw >> 16); tl[n4 + 3][k] = (short)pw;
    }
    __syncthreads();
    #pragma unroll
    for (int p = 0; p < 4; ++p) {
        int n = p * 16 + (tid >> 4);
        int k4 = (tid & 15) << 2;
        if (n0 + n >= H_DIM) continue;
        short4 sh = { th[n][k4], th[n][k4 + 1], th[n][k4 + 2], th[n][k4 + 3] };
        short4 sl = { tl[n][k4], tl[n][k4 + 1], tl[n][k4 + 2], tl[n][k4 + 3] };
        *(short4*)(ohz + (size_t)(n0 + n) * 64 + k4) = sh;
        *(short4*)(olz + (size_t)(n0 + n) * 64 + k4) = sl;
    }
}

// big weights [600][600] -> hi/lo [600][HP] (k zero-padded 600..607)
__global__ __launch_bounds__(256)
void wts_big_k(const float* __restrict__ w2, const float* __restrict__ l1,
               const float* __restrict__ l2, const float* __restrict__ iw,
               short* __restrict__ oh2, short* __restrict__ ol2,
               short* __restrict__ oh1, short* __restrict__ ol1,
               short* __restrict__ ohl2, short* __restrict__ oll2,
               short* __restrict__ ohi, short* __restrict__ oli)
{
    __shared__ short th[64][65], tl[64][65];
    const int z = blockIdx.z, type = z / L_LAYERS, layer = z % L_LAYERS;
    const float* w; short* oh; short* ol;
    if (type == 0)      { w = w2; oh = oh2; ol = ol2; }
    else if (type == 1) { w = l1; oh = oh1; ol = ol1; }
    else if (type == 2) { w = l2; oh = ohl2; ol = oll2; }
    else                { w = iw; oh = ohi; ol = oli; }
    w  += (size_t)layer * H_DIM * H_DIM;
    oh += (size_t)layer * H_DIM * HP;
    ol += (size_t)layer * H_DIM * HP;
    const int k0 = blockIdx.x * 64, n0 = blockIdx.y * 64;
    const int tid = threadIdx.x;
    #pragma unroll
    for (int p = 0; p < 4; ++p) {
        int k = p * 16 + (tid >> 4);
        int n4 = (tid & 15) << 2;
        float4 v = make_float4(0.f, 0.f, 0.f, 0.f);
        if (k0 + k < H_DIM && n0 + n4 + 3 < H_DIM)
            v = *(const float4*)(w + (size_t)(k0 + k) * H_DIM + n0 + n4);
        int px = packsplit(v.x), py = packsplit(v.y);
        int pz = packsplit(v.z), pw = packsplit(v.w);
        th[n4 + 0][k] = (short)(px >> 16); tl[n4 + 0][k] = (short)px;
        th[n4 + 1][k] = (short)(py >> 16); tl[n4 + 1][k] = (short)py;
        th[n4 + 2][k] = (short)(pz >> 16); tl[n4 + 2][k] = (short)pz;
        th[n4 + 3][k] = (short)(pw >> 16); tl[n4 + 3][k] = (short)pw;
    }
    __syncthreads();
    #pragma unroll
    for (int p = 0; p < 4; ++p) {
        int n = p * 16 + (tid >> 4);
        int k4 = (tid & 15) << 2;
        if (n0 + n >= H_DIM || k0 + k4 > HP - 4) continue;
        short4 sh = { th[n][k4], th[n][k4 + 1], th[n][k4 + 2], th[n][k4 + 3] };
        short4 sl = { tl[n][k4], tl[n][k4 + 1], tl[n][k4 + 2], tl[n][k4 + 3] };
        *(short4*)(oh + (size_t)(n0 + n) * HP + k0 + k4) = sh;
        *(short4*)(ol + (size_t)(n0 + n) * HP + k0 + k4) = sl;
    }
}

// ---------------------------------------------------------------- helpers
__global__ __launch_bounds__(256)
void init_h_k(const int* __restrict__ z, const float* __restrict__ emb,
              float* __restrict__ h, int* __restrict__ hP)
{
    int t = blockIdx.x * 256 + threadIdx.x;
    const int QC = HP / 4;   // 152
    if (t >= N_ATOMS * QC) return;
    int i = t / QC;
    int q = (t - i * QC) << 2;
    size_t idx = (size_t)i * HP + q;
    if (q < H_DIM) {
        float4 v = *(const float4*)(emb + (size_t)z[i] * H_DIM + q);
        *(float4*)(h + idx) = v;
        *(int4*)(hP + idx) = make_int4(packsplit(v.x), packsplit(v.y),
                                       packsplit(v.z), packsplit(v.w));
    } else {
        *(float4*)(h + idx) = make_float4(0.f, 0.f, 0.f, 0.f);
        *(int4*)(hP + idx) = make_int4(0, 0, 0, 0);
    }
}

// per-edge record: {src*HP, i0*HP, a = C - f*C, b = f*C}
__global__ __launch_bounds__(256)
void edge_geom_k(const float* __restrict__ pos, const int* __restrict__ src,
                 const int* __restrict__ dst, float4* __restrict__ einfo)
{
    int e = blockIdx.x * 256 + threadIdx.x;
    if (e >= E_EDGES) return;
    int s = src[e], d0 = dst[e];
    float dx = pos[s * 3 + 0] - pos[d0 * 3 + 0];
    float dy = pos[s * 3 + 1] - pos[d0 * 3 + 1];
    float dz = pos[s * 3 + 2] - pos[d0 * 3 + 2];
    float dist = sqrtf(dx * dx + dy * dy + dz * dz + 1e-12f);
    float cc = 0.5f * (cosf(dist * 0.31415926535f) + 1.0f);
    float u = dist * ((float)(M_TAB - 1) / DMAX);
    u = fminf(fmaxf(u, 0.0f), (float)(M_TAB - 1) - 0.001f);
    int i0 = (int)u;
    float fc = (u - (float)i0) * cc;
    einfo[e] = make_float4(__int_as_float(s * HP),
                           __int_as_float(i0 * HP),
                           cc - fc, fc);
}

// rbf table [M_TAB][64] packed, zero for g >= 50
__global__ __launch_bounds__(256)
void rbf_tab_k(int* __restrict__ rtabP)
{
    int t = blockIdx.x * 256 + threadIdx.x;
    if (t >= M_TAB * 64) return;
    int i = t >> 6, g = t & 63;
    float v = 0.0f;
    if (g < G_DIM) {
        float dg  = (float)i * (DMAX / (float)(M_TAB - 1));
        float off = (float)g * (10.0f / 49.0f);
        float x = dg - off;
        const float coeff = -0.5f * (49.0f / 10.0f) * (49.0f / 10.0f);
        v = expf(coeff * x * x);
    }
    rtabP[t] = packsplit(v);
}

// ---------------------------------------------------------------- CSR build
__global__ __launch_bounds__(256)
void hist_k(const int* __restrict__ dst, int* __restrict__ deg)
{
    int e = blockIdx.x * 256 + threadIdx.x;
    if (e >= E_EDGES) return;
    atomicAdd(&deg[dst[e]], 1);
}

__global__ __launch_bounds__(1024)
void scan_k(const int* __restrict__ deg, int* __restrict__ rowptr)
{
    __shared__ int sums[1024];
    int tid = threadIdx.x;
    const int CHUNK = (N_ATOMS + 1023) / 1024;
    int base = tid * CHUNK;
    int local[16];
    int s = 0;
    #pragma unroll
    for (int c = 0; c < 16; ++c) {
        if (c >= CHUNK) break;
        int idx = base + c;
        local[c] = s;
        s += (idx < N_ATOMS) ? deg[idx] : 0;
    }
    sums[tid] = s;
    __syncthreads();
    for (int off = 1; off < 1024; off <<= 1) {
        int v = (tid >= off) ? sums[tid - off] : 0;
        __syncthreads();
        sums[tid] += v;
        __syncthreads();
    }
    int prefix = (tid > 0) ? sums[tid - 1] : 0;
    #pragma unroll
    for (int c = 0; c < 16; ++c) {
        if (c >= CHUNK) break;
        int idx = base + c;
        if (idx <= N_ATOMS) rowptr[idx] = prefix + local[c];
    }
    if (tid == 1023) rowptr[N_ATOMS] = sums[1023];
}

__global__ __launch_bounds__(256)
void fill_k(const int* __restrict__ dst, const float4* __restrict__ einfo,
            const int* __restrict__ rowptr, int* __restrict__ cursor,
            float4* __restrict__ esorted)
{
    int e = blockIdx.x * 256 + threadIdx.x;
    if (e >= E_EDGES) return;
    int d0 = dst[e];
    int pos = rowptr[d0] + atomicAdd(&cursor[d0], 1);
    esorted[pos] = einfo[e];
}

// ---------------------------------------------------------------- gather
__global__ __launch_bounds__(256)
void gather_k(const int* __restrict__ yP, const int* __restrict__ wtP,
              const int* __restrict__ rowptr, const float4* __restrict__ esorted,
              int* __restrict__ aggP)
{
    int t = blockIdx.x * 256 + threadIdx.x;
    const int QC = HP / 4;   // 152
    if (t >= N_ATOMS * QC) return;
    int i = t / QC;
    int q = (t - i * QC) << 2;
    size_t idx = (size_t)i * HP + q;
    if (q >= H_DIM) { *(int4*)(aggP + idx) = make_int4(0, 0, 0, 0); return; }
    int j0 = rowptr[i], j1 = rowptr[i + 1];
    float4 acc = make_float4(0.f, 0.f, 0.f, 0.f);
    for (int j = j0; j < j1; ++j) {
        float4 ei = esorted[j];
        int srow = __float_as_int(ei.x);
        int wrow = __float_as_int(ei.y);
        float a = ei.z, b = ei.w;
        int4 yv = *(const int4*)(yP + srow + q);
        int4 w0 = *(const int4*)(wtP + wrow + q);
        int4 w1 = *(const int4*)(wtP + wrow + HP + q);
        acc.x += unpackf(yv.x) * (a * unpackf(w0.x) + b * unpackf(w1.x));
        acc.y += unpackf(yv.y) * (a * unpackf(w0.y) + b * unpackf(w1.y));
        acc.z += unpackf(yv.z) * (a * unpackf(w0.z) + b * unpackf(w1.z));
        acc.w += unpackf(yv.w) * (a * unpackf(w0.w) + b * unpackf(w1.w));
    }
    *(int4*)(aggP + idx) = make_int4(packsplit(acc.x), packsplit(acc.y),
                                     packsplit(acc.z), packsplit(acc.w));
}

// ---------------------------------------------------------------- pool
__global__ __launch_bounds__(256)
void pool_sum_k(const float* __restrict__ h, const int* __restrict__ batch,
                float* __restrict__ sums)
{
    int t = blockIdx.x * 256 + threadIdx.x;
    const int QH = H_DIM / 4;   // 150
    if (t >= N_ATOMS * QH) return;
    int i = t / QH;
    int q = (t - i * QH) << 2;
    int b = batch[i];
    const float4 hv = *(const float4*)(h + (size_t)i * HP + q);
    float* sp = sums + (size_t)b * H_DIM + q;
    atomicAdd(sp + 0, hv.x);
    atomicAdd(sp + 1, hv.y);
    atomicAdd(sp + 2, hv.z);
    atomicAdd(sp + 3, hv.w);
}

__global__ __launch_bounds__(256)
void cnt_k(const int* __restrict__ batch, float* __restrict__ cnt)
{
    int i = blockIdx.x * 256 + threadIdx.x;
    if (i >= N_ATOMS) return;
    atomicAdd(&cnt[batch[i]], 1.0f);
}

__global__ __launch_bounds__(256)
void pool_div_k(float* __restrict__ sums, const float* __restrict__ cnt)
{
    int t = blockIdx.x * 256 + threadIdx.x;
    if (t >= B_MOLS * H_DIM) return;
    sums[t] /= fmaxf(cnt[t / H_DIM], 1.0f);
}

// ---------------------------------------------------------------- launch
extern "C" void kernel_launch(void* const* d_in, const int* in_sizes, int n_in,
                              void* d_out, int out_size, void* d_ws, size_t ws_size,
                              hipStream_t stream)
{
    const int*   z      = (const int*)  d_in[0];
    const float* pos    = (const float*)d_in[1];
    const int*   batch  = (const int*)  d_in[2];
    const int*   eidx   = (const int*)  d_in[3];
    const float* emb    = (const float*)d_in[4];
    const float* mlp_w1 = (const float*)d_in[5];
    const float* mlp_b1 = (const float*)d_in[6];
    const float* mlp_w2 = (const float*)d_in[7];
    const float* mlp_b2 = (const float*)d_in[8];
    const float* lin1_w = (const float*)d_in[9];
    const float* lin2_w = (const float*)d_in[10];
    const float* lin2_b = (const float*)d_in[11];
    const float* intw   = (const float*)d_in[12];
    const float* intb   = (const float*)d_in[13];
    const float* poolw  = (const float*)d_in[14];
    const float* poolb  = (const float*)d_in[15];

    float* ws = (float*)d_ws;
    const size_t NHP = (size_t)N_ATOMS * HP;       // 6,080,000
    const size_t THP = (size_t)M_TAB * HP;         // 622,592
    float* h     = ws;                             // fp32 master
    int*   hP    = (int*)(ws + NHP);               // packed split
    int*   y1P   = (int*)(ws + 2 * NHP);           // packed; aliases tP
    int*   tP    = y1P;
    int*   aggP  = (int*)(ws + 3 * NHP);
    // aggP region aliases (dead at those phases):
    float4* einfo  = (float4*)aggP;                          // 256,000 f
    int*    deg    = (int*)((float*)aggP + 300000);          // 10,000
    int*    cursor = (int*)((float*)aggP + 310000);          // 10,000
    float*  sums   = (float*)aggP + 320000;                  // 76,800
    float*  cnt    = (float*)aggP + 396800;                  // 128
    int*   ttabP = (int*)(ws + 4 * NHP);           // 622,592
    int*   wtabP = (int*)(ws + 4 * NHP + THP);     // 622,592
    int*   rtabP = (int*)(ws + 4 * NHP + 2 * THP); // M_TAB*64 = 65,536
    short* wtH   = (short*)(ws + 4 * NHP + 2 * THP + (size_t)M_TAB * 64);
    short* wtL   = wtH + 8985600;
    float4* esorted = (float4*)((float*)(wtL + 8985600));    // 256,000 f
    int*    rowptr  = (int*)((float*)esorted + 256000);      // 10,001

    short* w1t_h = wtH;                       short* w1t_l = wtL;
    short* w2t_h = wtH + 230400;              short* w2t_l = wtL + 230400;
    short* l1t_h = w2t_h + 6 * 600 * HP;      short* l1t_l = w2t_l + 6 * 600 * HP;
    short* l2t_h = l1t_h + 6 * 600 * HP;      short* l2t_l = l1t_l + 6 * 600 * HP;
    short* int_h = l2t_h + 6 * 600 * HP;      short* int_l = l2t_l + 6 * 600 * HP;

    const int* src = eidx;
    const int* dst = eidx + E_EDGES;

    const dim3 blk(256);
    const int QC = HP / 4;
    const dim3 gN = mfma_grid(N_ATOMS, H_DIM);   // 160*10 = 1600
    const dim3 gT = mfma_grid(M_TAB, H_DIM);     // 16*10  = 160

    // ---- one-time prep (einfo/deg/cursor alias aggP: all dead before gather)
    edge_geom_k<<<(E_EDGES + 255) / 256, blk, 0, stream>>>(pos, src, dst, einfo);
    hipMemsetAsync(deg, 0, 2 * N_ATOMS * sizeof(int), stream);
    hist_k <<<(E_EDGES + 255) / 256, blk, 0, stream>>>(dst, deg);
    scan_k <<<1, 1024, 0, stream>>>(deg, rowptr);
    fill_k <<<(E_EDGES + 255) / 256, blk, 0, stream>>>(dst, einfo, rowptr, cursor, esorted);
    init_h_k <<<(N_ATOMS * QC + 255) / 256, blk, 0, stream>>>(z, emb, h, hP);
    rbf_tab_k<<<(M_TAB * 64 + 255) / 256,   blk, 0, stream>>>(rtabP);
    wts_w1_k  <<<dim3(1, 10, 6),   blk, 0, stream>>>(mlp_w1, w1t_h, w1t_l);
    wts_big_k <<<dim3(10, 10, 24), blk, 0, stream>>>(
        mlp_w2, lin1_w, lin2_w, intw,
        w2t_h, w2t_l, l1t_h, l1t_l, l2t_h, l2t_l, int_h, int_l);

    for (int k = 0; k < L_LAYERS; ++k) {
        const float* b1  = mlp_b1 + (size_t)k * H_DIM;
        const float* b2  = mlp_b2 + (size_t)k * H_DIM;
        const float* l2b = lin2_b + (size_t)k * H_DIM;
        const float* ib  = intb   + (size_t)k * H_DIM;
        const short* w1h = w1t_h + (size_t)k * H_DIM * 64;
        const short* w1l = w1t_l + (size_t)k * H_DIM * 64;
        const short* w2h = w2t_h + (size_t)k * H_DIM * HP;
        const short* w2l = w2t_l + (size_t)k * H_DIM * HP;
        const short* l1h = l1t_h + (size_t)k * H_DIM * HP;
        const short* l1l = l1t_l + (size_t)k * H_DIM * HP;
        const short* l2h = l2t_h + (size_t)k * H_DIM * HP;
        const short* l2l = l2t_l + (size_t)k * H_DIM * HP;
        const short* ih  = int_h + (size_t)k * H_DIM * HP;
        const short* il  = int_l + (size_t)k * H_DIM * HP;

        // ttabP = packsplit(ssp(rtab @ w1 + b1))   [M_TAB x 600], K=64
        gemm_mfma<true, true, false, false, true><<<gT, blk, 0, stream>>>(
            rtabP, 64, w1h, w1l, 64, b1,
            nullptr, ttabP, M_TAB, 64, H_DIM);
        // wtabP = packsplit(ttab @ w2 + b2)        [M_TAB x 600], K=HP
        gemm_mfma<true, false, false, false, true><<<gT, blk, 0, stream>>>(
            ttabP, HP, w2h, w2l, HP, b2,
            nullptr, wtabP, M_TAB, HP, H_DIM);
        // y1P = packsplit(h @ lin1)                [N x 600]
        gemm_mfma<false, false, false, false, true><<<gN, blk, 0, stream>>>(
            hP, HP, l1h, l1l, HP, nullptr,
            nullptr, y1P, N_ATOMS, HP, H_DIM);
        // aggP = packsplit(CSR-gather(y1 * W(d) * C))
        gather_k<<<(N_ATOMS * QC + 255) / 256, blk, 0, stream>>>(
            y1P, wtabP, rowptr, esorted, aggP);
        // tP = packsplit(ssp(agg @ lin2 + b))      (aliases y1P)
        gemm_mfma<true, true, false, false, true><<<gN, blk, 0, stream>>>(
            aggP, HP, l2h, l2l, HP, l2b,
            nullptr, tP, N_ATOMS, HP, H_DIM);
        // h += t @ int_w + ib  (fp32 master + refresh packed split)
        gemm_mfma<true, false, true, true, true><<<gN, blk, 0, stream>>>(
            tP, HP, ih, il, HP, ib,
            h, hP, N_ATOMS, HP, H_DIM);
    }

    // mean pool per molecule, then out = pooled @ pool_w + pool_b
    hipMemsetAsync(sums, 0, (size_t)(B_MOLS * H_DIM + B_MOLS) * sizeof(float), stream);
    pool_sum_k<<<(N_ATOMS * (H_DIM / 4) + 255) / 256, blk, 0, stream>>>(h, batch, sums);
    cnt_k     <<<(N_ATOMS + 255) / 256,      blk, 0, stream>>>(batch, cnt);
    pool_div_k<<<(B_MOLS * H_DIM + 255) / 256, blk, 0, stream>>>(sums, cnt);
    gemm_k<true><<<dim3((H_DIM + BN - 1) / BN, (B_MOLS + BM - 1) / BM), blk, 0, stream>>>(
        sums, H_DIM, poolw, poolb, (float*)d_out, B_MOLS, H_DIM, H_DIM);
}

// Round 8
// 1327.583 us; speedup vs baseline: 2.4597x; 1.1723x over previous
//
#include <hip/hip_runtime.h>
#include <math.h>

// SchNet forward, MI355X. Round 8 = round 7 with the aliasing crash fixed:
// mrow/pooled were inside the aggP region, which gather_k fully rewrites
// every layer -> pool_seg_k read clobbered bounds -> OOB -> core dump.
// They now live in the persistent tail (after esorted), nothing aliases them.
// r7 features: segment-mean pool (no atomics), batched 6-layer table slab
// GEMMs, packed-only bf16 hi/lo residual, x2-unrolled gather/pool.
// r6: 64x64 MFMA tiles launch_bounds(256,6). r5: packed hi/lo + HP=608
// sector alignment. r4: XCD swizzle. r2: CSR gather. r1: filter table+lerp.

#define N_ATOMS 10000
#define E_EDGES 64000
#define B_MOLS  128
#define H_DIM   600
#define HP      608            // padded leading dim (608*4B = 38 sectors)
#define G_DIM   50
#define L_LAYERS 6
#define M_TAB   1024
#define DMAX    8.67f
#define LOG2C   0.69314718056f

#define TM 64
#define TN 64
#define TK 32
#define SA 40          // LDS row stride in shorts (80B rows)

typedef __attribute__((ext_vector_type(8))) short bf16x8;
typedef __attribute__((ext_vector_type(4))) float f32x4;

__device__ __forceinline__ float sspf(float x) {
    return fmaxf(x, 0.0f) + log1pf(expf(-fabsf(x))) - LOG2C;
}
__device__ __forceinline__ short f2bf(float x) {
    unsigned u = __float_as_uint(x);
    unsigned r = (u + 0x7FFF + ((u >> 16) & 1)) >> 16;   // RNE
    return (short)r;
}
__device__ __forceinline__ float bf2f(short h) {
    return __uint_as_float(((unsigned)(unsigned short)h) << 16);
}
__device__ __forceinline__ int packsplit(float x) {
    short hi = f2bf(x);
    short lo = f2bf(x - bf2f(hi));
    return ((int)hi << 16) | ((int)lo & 0xffff);
}
__device__ __forceinline__ float unpackf(int p) {
    float fh = __uint_as_float((unsigned)p & 0xffff0000u);
    float fl = __uint_as_float(((unsigned)p) << 16);
    return fh + fl;
}

// ---------------------------------------------------------------- MFMA GEMM
// outP = packsplit(op(A @ B + bias [+ unpack(outP)])). A: packed int [Ma][lda]
// (zero-padded cols). B: TRANSPOSED pre-split bf16 hi/lo [Nc][ldb] (zero-
// padded k). K % 32 == 0. Output ld = HP, pad cols 0. 1D grid, XCD swizzle.
template<bool BIAS, bool ACT, bool ACCUM>
__global__ __launch_bounds__(256, 6)
void gemm_mfma(const int* __restrict__ A, int lda,
               const short* __restrict__ Bh, const short* __restrict__ Bl, int ldb,
               const float* __restrict__ bias,
               int* __restrict__ outP,
               int Ma, int K, int Nc)
{
    const int NT = (Nc + TN - 1) / TN;
    const int f = blockIdx.x;
    const int xcd = f & 7, s = f >> 3;
    const int n0 = (s % NT) * TN;
    const int m0 = (xcd + 8 * (s / NT)) * TM;
    if (m0 >= Ma) return;

    __shared__ __align__(16) short As[2][TM * SA];
    __shared__ __align__(16) short Bs[2][TN * SA];

    const int tid = threadIdx.x;
    const int lane = tid & 63, wid = tid >> 6;
    const int wm = (wid >> 1) * 32, wn = (wid & 1) * 32;
    const int l15 = lane & 15, quad = lane >> 4;
    const int srow = tid >> 2;          // 0..63
    const int skk  = (tid & 3) << 3;    // 0,8,16,24

    f32x4 acc[2][2];
    #pragma unroll
    for (int i = 0; i < 2; ++i)
        #pragma unroll
        for (int j = 0; j < 2; ++j)
            acc[i][j] = (f32x4){0.f, 0.f, 0.f, 0.f};

    int4 ra0, ra1;
    short4 rbh0, rbh1, rbl0, rbl1;

    {   // prefetch chunk 0
        int gm = m0 + srow;
        if (gm < Ma) {
            const int* ap = A + (size_t)gm * lda + skk;
            ra0 = *(const int4*)ap; ra1 = *(const int4*)(ap + 4);
        } else { ra0 = make_int4(0,0,0,0); ra1 = make_int4(0,0,0,0); }
        int gn = n0 + srow;
        if (gn < Nc) {
            const short* bp = Bh + (size_t)gn * ldb + skk;
            const short* lp = Bl + (size_t)gn * ldb + skk;
            rbh0 = *(const short4*)bp; rbh1 = *(const short4*)(bp + 4);
            rbl0 = *(const short4*)lp; rbl1 = *(const short4*)(lp + 4);
        } else { rbh0 = {0,0,0,0}; rbh1 = {0,0,0,0};
                 rbl0 = {0,0,0,0}; rbl1 = {0,0,0,0}; }
    }

    for (int k0 = 0; k0 < K; k0 += TK) {
        {
            short4 vh0 = { (short)(ra0.x >> 16), (short)(ra0.y >> 16),
                           (short)(ra0.z >> 16), (short)(ra0.w >> 16) };
            short4 vl0 = { (short)ra0.x, (short)ra0.y, (short)ra0.z, (short)ra0.w };
            short4 vh1 = { (short)(ra1.x >> 16), (short)(ra1.y >> 16),
                           (short)(ra1.z >> 16), (short)(ra1.w >> 16) };
            short4 vl1 = { (short)ra1.x, (short)ra1.y, (short)ra1.z, (short)ra1.w };
            *(short4*)&As[0][srow * SA + skk]     = vh0;
            *(short4*)&As[0][srow * SA + skk + 4] = vh1;
            *(short4*)&As[1][srow * SA + skk]     = vl0;
            *(short4*)&As[1][srow * SA + skk + 4] = vl1;
            *(short4*)&Bs[0][srow * SA + skk]     = rbh0;
            *(short4*)&Bs[0][srow * SA + skk + 4] = rbh1;
            *(short4*)&Bs[1][srow * SA + skk]     = rbl0;
            *(short4*)&Bs[1][srow * SA + skk + 4] = rbl1;
        }
        __syncthreads();

        int kn = k0 + TK;
        if (kn < K) {
            int gm = m0 + srow;
            if (gm < Ma) {
                const int* ap = A + (size_t)gm * lda + kn + skk;
                ra0 = *(const int4*)ap; ra1 = *(const int4*)(ap + 4);
            } else { ra0 = make_int4(0,0,0,0); ra1 = make_int4(0,0,0,0); }
            int gn = n0 + srow;
            if (gn < Nc) {
                const short* bp = Bh + (size_t)gn * ldb + kn + skk;
                const short* lp = Bl + (size_t)gn * ldb + kn + skk;
                rbh0 = *(const short4*)bp; rbh1 = *(const short4*)(bp + 4);
                rbl0 = *(const short4*)lp; rbl1 = *(const short4*)(lp + 4);
            } else { rbh0 = {0,0,0,0}; rbh1 = {0,0,0,0};
                     rbl0 = {0,0,0,0}; rbl1 = {0,0,0,0}; }
        }

        bf16x8 a_h[2], a_l[2], b_h[2], b_l[2];
        #pragma unroll
        for (int mi = 0; mi < 2; ++mi) {
            int row = wm + mi * 16 + l15;
            a_h[mi] = *(const bf16x8*)&As[0][row * SA + quad * 8];
            a_l[mi] = *(const bf16x8*)&As[1][row * SA + quad * 8];
        }
        #pragma unroll
        for (int ni = 0; ni < 2; ++ni) {
            int col = wn + ni * 16 + l15;
            b_h[ni] = *(const bf16x8*)&Bs[0][col * SA + quad * 8];
            b_l[ni] = *(const bf16x8*)&Bs[1][col * SA + quad * 8];
        }

        #pragma unroll
        for (int mi = 0; mi < 2; ++mi)
            #pragma unroll
            for (int ni = 0; ni < 2; ++ni) {
                acc[mi][ni] = __builtin_amdgcn_mfma_f32_16x16x32_bf16(
                    a_h[mi], b_h[ni], acc[mi][ni], 0, 0, 0);
                acc[mi][ni] = __builtin_amdgcn_mfma_f32_16x16x32_bf16(
                    a_h[mi], b_l[ni], acc[mi][ni], 0, 0, 0);
                acc[mi][ni] = __builtin_amdgcn_mfma_f32_16x16x32_bf16(
                    a_l[mi], b_h[ni], acc[mi][ni], 0, 0, 0);
            }
        __syncthreads();
    }

    #pragma unroll
    for (int mi = 0; mi < 2; ++mi) {
        #pragma unroll
        for (int r = 0; r < 4; ++r) {
            int row = m0 + wm + mi * 16 + quad * 4 + r;
            if (row >= Ma) continue;
            #pragma unroll
            for (int ni = 0; ni < 2; ++ni) {
                int col = n0 + wn + ni * 16 + l15;
                if (col >= HP) continue;
                size_t idx = (size_t)row * HP + col;
                float v = 0.0f;
                if (col < Nc) {
                    v = acc[mi][ni][r];
                    if constexpr (BIAS) v += bias[col];
                    if constexpr (ACT)  v = sspf(v);
                    if constexpr (ACCUM) v += unpackf(outP[idx]);
                }
                outP[idx] = packsplit(v);
            }
        }
    }
}

// Batched slab GEMM over all L layers stacked in M (1024 rows per layer).
// SHAREDA: A rows are (m % 1024) (rtab shared across layers). B/bias indexed
// by layer = m/1024 with strides bstride / 600.
template<bool SHAREDA, bool ACT>
__global__ __launch_bounds__(256, 6)
void gemm_tab(const int* __restrict__ A, int lda,
              const short* __restrict__ BhBase, const short* __restrict__ BlBase,
              int ldb, int bstride,
              const float* __restrict__ biasBase,
              int* __restrict__ outP,
              int Ma, int K, int Nc)
{
    const int NT = (Nc + TN - 1) / TN;
    const int f = blockIdx.x;
    const int xcd = f & 7, s = f >> 3;
    const int n0 = (s % NT) * TN;
    const int m0 = (xcd + 8 * (s / NT)) * TM;
    if (m0 >= Ma) return;

    const int layer = m0 >> 10;                       // 1024 rows per layer
    const int arow0 = SHAREDA ? (m0 & 1023) : m0;
    const short* __restrict__ Bh = BhBase + (size_t)layer * bstride;
    const short* __restrict__ Bl = BlBase + (size_t)layer * bstride;
    const float* __restrict__ bias = biasBase + (size_t)layer * H_DIM;

    __shared__ __align__(16) short As[2][TM * SA];
    __shared__ __align__(16) short Bs[2][TN * SA];

    const int tid = threadIdx.x;
    const int lane = tid & 63, wid = tid >> 6;
    const int wm = (wid >> 1) * 32, wn = (wid & 1) * 32;
    const int l15 = lane & 15, quad = lane >> 4;
    const int srow = tid >> 2;
    const int skk  = (tid & 3) << 3;

    f32x4 acc[2][2];
    #pragma unroll
    for (int i = 0; i < 2; ++i)
        #pragma unroll
        for (int j = 0; j < 2; ++j)
            acc[i][j] = (f32x4){0.f, 0.f, 0.f, 0.f};

    int4 ra0, ra1;
    short4 rbh0, rbh1, rbl0, rbl1;
    {
        const int* ap = A + (size_t)(arow0 + srow) * lda + skk;
        ra0 = *(const int4*)ap; ra1 = *(const int4*)(ap + 4);
        int gn = n0 + srow;
        if (gn < Nc) {
            const short* bp = Bh + (size_t)gn * ldb + skk;
            const short* lp = Bl + (size_t)gn * ldb + skk;
            rbh0 = *(const short4*)bp; rbh1 = *(const short4*)(bp + 4);
            rbl0 = *(const short4*)lp; rbl1 = *(const short4*)(lp + 4);
        } else { rbh0 = {0,0,0,0}; rbh1 = {0,0,0,0};
                 rbl0 = {0,0,0,0}; rbl1 = {0,0,0,0}; }
    }

    for (int k0 = 0; k0 < K; k0 += TK) {
        {
            short4 vh0 = { (short)(ra0.x >> 16), (short)(ra0.y >> 16),
                           (short)(ra0.z >> 16), (short)(ra0.w >> 16) };
            short4 vl0 = { (short)ra0.x, (short)ra0.y, (short)ra0.z, (short)ra0.w };
            short4 vh1 = { (short)(ra1.x >> 16), (short)(ra1.y >> 16),
                           (short)(ra1.z >> 16), (short)(ra1.w >> 16) };
            short4 vl1 = { (short)ra1.x, (short)ra1.y, (short)ra1.z, (short)ra1.w };
            *(short4*)&As[0][srow * SA + skk]     = vh0;
            *(short4*)&As[0][srow * SA + skk + 4] = vh1;
            *(short4*)&As[1][srow * SA + skk]     = vl0;
            *(short4*)&As[1][srow * SA + skk + 4] = vl1;
            *(short4*)&Bs[0][srow * SA + skk]     = rbh0;
            *(short4*)&Bs[0][srow * SA + skk + 4] = rbh1;
            *(short4*)&Bs[1][srow * SA + skk]     = rbl0;
            *(short4*)&Bs[1][srow * SA + skk + 4] = rbl1;
        }
        __syncthreads();

        int kn = k0 + TK;
        if (kn < K) {
            const int* ap = A + (size_t)(arow0 + srow) * lda + kn + skk;
            ra0 = *(const int4*)ap; ra1 = *(const int4*)(ap + 4);
            int gn = n0 + srow;
            if (gn < Nc) {
                const short* bp = Bh + (size_t)gn * ldb + kn + skk;
                const short* lp = Bl + (size_t)gn * ldb + kn + skk;
                rbh0 = *(const short4*)bp; rbh1 = *(const short4*)(bp + 4);
                rbl0 = *(const short4*)lp; rbl1 = *(const short4*)(lp + 4);
            } else { rbh0 = {0,0,0,0}; rbh1 = {0,0,0,0};
                     rbl0 = {0,0,0,0}; rbl1 = {0,0,0,0}; }
        }

        bf16x8 a_h[2], a_l[2], b_h[2], b_l[2];
        #pragma unroll
        for (int mi = 0; mi < 2; ++mi) {
            int row = wm + mi * 16 + l15;
            a_h[mi] = *(const bf16x8*)&As[0][row * SA + quad * 8];
            a_l[mi] = *(const bf16x8*)&As[1][row * SA + quad * 8];
        }
        #pragma unroll
        for (int ni = 0; ni < 2; ++ni) {
            int col = wn + ni * 16 + l15;
            b_h[ni] = *(const bf16x8*)&Bs[0][col * SA + quad * 8];
            b_l[ni] = *(const bf16x8*)&Bs[1][col * SA + quad * 8];
        }
        #pragma unroll
        for (int mi = 0; mi < 2; ++mi)
            #pragma unroll
            for (int ni = 0; ni < 2; ++ni) {
                acc[mi][ni] = __builtin_amdgcn_mfma_f32_16x16x32_bf16(
                    a_h[mi], b_h[ni], acc[mi][ni], 0, 0, 0);
                acc[mi][ni] = __builtin_amdgcn_mfma_f32_16x16x32_bf16(
                    a_h[mi], b_l[ni], acc[mi][ni], 0, 0, 0);
                acc[mi][ni] = __builtin_amdgcn_mfma_f32_16x16x32_bf16(
                    a_l[mi], b_h[ni], acc[mi][ni], 0, 0, 0);
            }
        __syncthreads();
    }

    #pragma unroll
    for (int mi = 0; mi < 2; ++mi) {
        #pragma unroll
        for (int r = 0; r < 4; ++r) {
            int row = m0 + wm + mi * 16 + quad * 4 + r;
            if (row >= Ma) continue;
            #pragma unroll
            for (int ni = 0; ni < 2; ++ni) {
                int col = n0 + wn + ni * 16 + l15;
                if (col >= HP) continue;
                float v = 0.0f;
                if (col < Nc) {
                    v = acc[mi][ni][r] + bias[col];
                    if constexpr (ACT) v = sspf(v);
                }
                outP[(size_t)row * HP + col] = packsplit(v);
            }
        }
    }
}

static inline dim3 mfma_grid(int Ma, int Nc) {
    int MB = (Ma + TM - 1) / TM;
    int NT = (Nc + TN - 1) / TN;
    int Ys = ((MB + 7) / 8) * 8;
    return dim3(Ys * NT);
}

// ---------------------------------------------------------------- fp32 GEMM (final pool matmul only)
#define BM 64
#define BN 64
#define BK 16
template<bool BIAS>
__global__ __launch_bounds__(256)
void gemm_k(const float* __restrict__ A, int lda,
            const float* __restrict__ W,
            const float* __restrict__ bias,
            float* __restrict__ out,
            int Ma, int K, int Nc)
{
    __shared__ __align__(16) float Asd[BK][BM];
    __shared__ __align__(16) float Bsd[BK][BN];
    const int tid = threadIdx.x;
    const int tx = tid & 15, ty = tid >> 4;
    const int m0 = blockIdx.y * BM, n0 = blockIdx.x * BN;
    const int ar = tid >> 2, ac = (tid & 3) << 2;
    const int br = tid >> 4, bc = (tid & 15) << 2;
    float acc[4][4] = {};
    for (int k0 = 0; k0 < K; k0 += BK) {
        {
            int row = m0 + ar, col = k0 + ac;
            float4 v = make_float4(0.f, 0.f, 0.f, 0.f);
            if (row < Ma) {
                const float* ap = A + (size_t)row * lda + col;
                if (col + 3 < K) v = *(const float4*)ap;
                else {
                    if (col + 0 < K) v.x = ap[0];
                    if (col + 1 < K) v.y = ap[1];
                    if (col + 2 < K) v.z = ap[2];
                }
            }
            Asd[ac + 0][ar] = v.x; Asd[ac + 1][ar] = v.y;
            Asd[ac + 2][ar] = v.z; Asd[ac + 3][ar] = v.w;
        }
        {
            int row = k0 + br, col = n0 + bc;
            float4 v = make_float4(0.f, 0.f, 0.f, 0.f);
            if (row < K && col + 3 < Nc)
                v = *(const float4*)(W + (size_t)row * Nc + col);
            *(float4*)&Bsd[br][bc] = v;
        }
        __syncthreads();
        #pragma unroll
        for (int kk = 0; kk < BK; ++kk) {
            float4 a4 = *(const float4*)&Asd[kk][ty << 2];
            float4 b4 = *(const float4*)&Bsd[kk][tx << 2];
            float av[4] = {a4.x, a4.y, a4.z, a4.w};
            float bv[4] = {b4.x, b4.y, b4.z, b4.w};
            #pragma unroll
            for (int i = 0; i < 4; ++i)
                #pragma unroll
                for (int j = 0; j < 4; ++j)
                    acc[i][j] = fmaf(av[i], bv[j], acc[i][j]);
        }
        __syncthreads();
    }
    #pragma unroll
    for (int i = 0; i < 4; ++i) {
        int row = m0 + (ty << 2) + i;
        if (row >= Ma) continue;
        #pragma unroll
        for (int j = 0; j < 4; ++j) {
            int col = n0 + (tx << 2) + j;
            if (col >= Nc) continue;
            float v = acc[i][j];
            if constexpr (BIAS) v += bias[col];
            out[(size_t)row * Nc + col] = v;
        }
    }
}

// ---------------------------------------------------------------- weight prep
__global__ __launch_bounds__(256)
void wts_w1_k(const float* __restrict__ w_all, short* __restrict__ oh,
              short* __restrict__ ol)
{
    __shared__ short th[64][65], tl[64][65];
    const int layer = blockIdx.z;
    const float* w = w_all + (size_t)layer * G_DIM * H_DIM;
    short* ohz = oh + (size_t)layer * H_DIM * 64;
    short* olz = ol + (size_t)layer * H_DIM * 64;
    const int n0 = blockIdx.y * 64;
    const int tid = threadIdx.x;
    #pragma unroll
    for (int p = 0; p < 4; ++p) {
        int k = p * 16 + (tid >> 4);
        int n4 = (tid & 15) << 2;
        float4 v = make_float4(0.f, 0.f, 0.f, 0.f);
        if (k < G_DIM && n0 + n4 + 3 < H_DIM)
            v = *(const float4*)(w + (size_t)k * H_DIM + n0 + n4);
        int px = packsplit(v.x), py = packsplit(v.y);
        int pz = packsplit(v.z), pw = packsplit(v.w);
        th[n4 + 0][k] = (short)(px >> 16); tl[n4 + 0][k] = (short)px;
        th[n4 + 1][k] = (short)(py >> 16); tl[n4 + 1][k] = (short)py;
        th[n4 + 2][k] = (short)(pz >> 16); tl[n4 + 2][k] = (short)pz;
        th[n4 + 3][k] = (short)(pw >> 16); tl[n4 + 3][k] = (short)pw;
    }
    __syncthreads();
    #pragma unroll
    for (int p = 0; p < 4; ++p) {
        int n = p * 16 + (tid >> 4);
        int k4 = (tid & 15) << 2;
        if (n0 + n >= H_DIM) continue;
        short4 sh = { th[n][k4], th[n][k4 + 1], th[n][k4 + 2], th[n][k4 + 3] };
        short4 sl = { tl[n][k4], tl[n][k4 + 1], tl[n][k4 + 2], tl[n][k4 + 3] };
        *(short4*)(ohz + (size_t)(n0 + n) * 64 + k4) = sh;
        *(short4*)(olz + (size_t)(n0 + n) * 64 + k4) = sl;
    }
}

__global__ __launch_bounds__(256)
void wts_big_k(const float* __restrict__ w2, const float* __restrict__ l1,
               const float* __restrict__ l2, const float* __restrict__ iw,
               short* __restrict__ oh2, short* __restrict__ ol2,
               short* __restrict__ oh1, short* __restrict__ ol1,
               short* __restrict__ ohl2, short* __restrict__ oll2,
               short* __restrict__ ohi, short* __restrict__ oli)
{
    __shared__ short th[64][65], tl[64][65];
    const int z = blockIdx.z, type = z / L_LAYERS, layer = z % L_LAYERS;
    const float* w; short* oh; short* ol;
    if (type == 0)      { w = w2; oh = oh2; ol = ol2; }
    else if (type == 1) { w = l1; oh = oh1; ol = ol1; }
    else if (type == 2) { w = l2; oh = ohl2; ol = oll2; }
    else                { w = iw; oh = ohi; ol = oli; }
    w  += (size_t)layer * H_DIM * H_DIM;
    oh += (size_t)layer * H_DIM * HP;
    ol += (size_t)layer * H_DIM * HP;
    const int k0 = blockIdx.x * 64, n0 = blockIdx.y * 64;
    const int tid = threadIdx.x;
    #pragma unroll
    for (int p = 0; p < 4; ++p) {
        int k = p * 16 + (tid >> 4);
        int n4 = (tid & 15) << 2;
        float4 v = make_float4(0.f, 0.f, 0.f, 0.f);
        if (k0 + k < H_DIM && n0 + n4 + 3 < H_DIM)
            v = *(const float4*)(w + (size_t)(k0 + k) * H_DIM + n0 + n4);
        int px = packsplit(v.x), py = packsplit(v.y);
        int pz = packsplit(v.z), pw = packsplit(v.w);
        th[n4 + 0][k] = (short)(px >> 16); tl[n4 + 0][k] = (short)px;
        th[n4 + 1][k] = (short)(py >> 16); tl[n4 + 1][k] = (short)py;
        th[n4 + 2][k] = (short)(pz >> 16); tl[n4 + 2][k] = (short)pz;
        th[n4 + 3][k] = (short)(pw >> 16); tl[n4 + 3][k] = (short)pw;
    }
    __syncthreads();
    #pragma unroll
    for (int p = 0; p < 4; ++p) {
        int n = p * 16 + (tid >> 4);
        int k4 = (tid & 15) << 2;
        if (n0 + n >= H_DIM || k0 + k4 > HP - 4) continue;
        short4 sh = { th[n][k4], th[n][k4 + 1], th[n][k4 + 2], th[n][k4 + 3] };
        short4 sl = { tl[n][k4], tl[n][k4 + 1], tl[n][k4 + 2], tl[n][k4 + 3] };
        *(short4*)(oh + (size_t)(n0 + n) * HP + k0 + k4) = sh;
        *(short4*)(ol + (size_t)(n0 + n) * HP + k0 + k4) = sl;
    }
}

// ---------------------------------------------------------------- helpers
__global__ __launch_bounds__(256)
void init_h_k(const int* __restrict__ z, const float* __restrict__ emb,
              int* __restrict__ hP)
{
    int t = blockIdx.x * 256 + threadIdx.x;
    const int QC = HP / 4;   // 152
    if (t >= N_ATOMS * QC) return;
    int i = t / QC;
    int q = (t - i * QC) << 2;
    size_t idx = (size_t)i * HP + q;
    if (q < H_DIM) {
        float4 v = *(const float4*)(emb + (size_t)z[i] * H_DIM + q);
        *(int4*)(hP + idx) = make_int4(packsplit(v.x), packsplit(v.y),
                                       packsplit(v.z), packsplit(v.w));
    } else {
        *(int4*)(hP + idx) = make_int4(0, 0, 0, 0);
    }
}

// per-edge record: {src*HP, i0*HP, a = C - f*C, b = f*C}
__global__ __launch_bounds__(256)
void edge_geom_k(const float* __restrict__ pos, const int* __restrict__ src,
                 const int* __restrict__ dst, float4* __restrict__ einfo)
{
    int e = blockIdx.x * 256 + threadIdx.x;
    if (e >= E_EDGES) return;
    int s = src[e], d0 = dst[e];
    float dx = pos[s * 3 + 0] - pos[d0 * 3 + 0];
    float dy = pos[s * 3 + 1] - pos[d0 * 3 + 1];
    float dz = pos[s * 3 + 2] - pos[d0 * 3 + 2];
    float dist = sqrtf(dx * dx + dy * dy + dz * dz + 1e-12f);
    float cc = 0.5f * (cosf(dist * 0.31415926535f) + 1.0f);
    float u = dist * ((float)(M_TAB - 1) / DMAX);
    u = fminf(fmaxf(u, 0.0f), (float)(M_TAB - 1) - 0.001f);
    int i0 = (int)u;
    float fc = (u - (float)i0) * cc;
    einfo[e] = make_float4(__int_as_float(s * HP),
                           __int_as_float(i0 * HP),
                           cc - fc, fc);
}

__global__ __launch_bounds__(256)
void rbf_tab_k(int* __restrict__ rtabP)
{
    int t = blockIdx.x * 256 + threadIdx.x;
    if (t >= M_TAB * 64) return;
    int i = t >> 6, g = t & 63;
    float v = 0.0f;
    if (g < G_DIM) {
        float dg  = (float)i * (DMAX / (float)(M_TAB - 1));
        float off = (float)g * (10.0f / 49.0f);
        float x = dg - off;
        const float coeff = -0.5f * (49.0f / 10.0f) * (49.0f / 10.0f);
        v = expf(coeff * x * x);
    }
    rtabP[t] = packsplit(v);
}

// ---------------------------------------------------------------- CSR build
__global__ __launch_bounds__(256)
void hist_k(const int* __restrict__ dst, int* __restrict__ deg)
{
    int e = blockIdx.x * 256 + threadIdx.x;
    if (e >= E_EDGES) return;
    atomicAdd(&deg[dst[e]], 1);
}

__global__ __launch_bounds__(1024)
void scan_k(const int* __restrict__ deg, int* __restrict__ rowptr)
{
    __shared__ int sums[1024];
    int tid = threadIdx.x;
    const int CHUNK = (N_ATOMS + 1023) / 1024;
    int base = tid * CHUNK;
    int local[16];
    int s = 0;
    #pragma unroll
    for (int c = 0; c < 16; ++c) {
        if (c >= CHUNK) break;
        int idx = base + c;
        local[c] = s;
        s += (idx < N_ATOMS) ? deg[idx] : 0;
    }
    sums[tid] = s;
    __syncthreads();
    for (int off = 1; off < 1024; off <<= 1) {
        int v = (tid >= off) ? sums[tid - off] : 0;
        __syncthreads();
        sums[tid] += v;
        __syncthreads();
    }
    int prefix = (tid > 0) ? sums[tid - 1] : 0;
    #pragma unroll
    for (int c = 0; c < 16; ++c) {
        if (c >= CHUNK) break;
        int idx = base + c;
        if (idx <= N_ATOMS) rowptr[idx] = prefix + local[c];
    }
    if (tid == 1023) rowptr[N_ATOMS] = sums[1023];
}

__global__ __launch_bounds__(256)
void fill_k(const int* __restrict__ dst, const float4* __restrict__ einfo,
            const int* __restrict__ rowptr, int* __restrict__ cursor,
            float4* __restrict__ esorted)
{
    int e = blockIdx.x * 256 + threadIdx.x;
    if (e >= E_EDGES) return;
    int d0 = dst[e];
    int pos = rowptr[d0] + atomicAdd(&cursor[d0], 1);
    esorted[pos] = einfo[e];
}

// molecule boundaries via binary search over the SORTED batch array
__global__ __launch_bounds__(256)
void bounds_k(const int* __restrict__ batch, int* __restrict__ mrow)
{
    int b = threadIdx.x;
    if (b > B_MOLS) return;
    int lo = 0, hi = N_ATOMS;
    while (lo < hi) {
        int mid = (lo + hi) >> 1;
        if (batch[mid] < b) lo = mid + 1; else hi = mid;
    }
    mrow[b] = lo;
}

// ---------------------------------------------------------------- gather
__device__ __forceinline__ void gacc(float4& acc, const int* yP, const int* wtP,
                                     const float4& ei, int q)
{
    int srow = __float_as_int(ei.x);
    int wrow = __float_as_int(ei.y);
    float a = ei.z, b = ei.w;
    int4 yv = *(const int4*)(yP + srow + q);
    int4 w0 = *(const int4*)(wtP + wrow + q);
    int4 w1 = *(const int4*)(wtP + wrow + HP + q);
    acc.x += unpackf(yv.x) * (a * unpackf(w0.x) + b * unpackf(w1.x));
    acc.y += unpackf(yv.y) * (a * unpackf(w0.y) + b * unpackf(w1.y));
    acc.z += unpackf(yv.z) * (a * unpackf(w0.z) + b * unpackf(w1.z));
    acc.w += unpackf(yv.w) * (a * unpackf(w0.w) + b * unpackf(w1.w));
}

__global__ __launch_bounds__(256)
void gather_k(const int* __restrict__ yP, const int* __restrict__ wtP,
              const int* __restrict__ rowptr, const float4* __restrict__ esorted,
              int* __restrict__ aggP)
{
    int t = blockIdx.x * 256 + threadIdx.x;
    const int QC = HP / 4;   // 152
    if (t >= N_ATOMS * QC) return;
    int i = t / QC;
    int q = (t - i * QC) << 2;
    size_t idx = (size_t)i * HP + q;
    if (q >= H_DIM) { *(int4*)(aggP + idx) = make_int4(0, 0, 0, 0); return; }
    int j0 = rowptr[i], j1 = rowptr[i + 1];
    float4 a0 = make_float4(0.f, 0.f, 0.f, 0.f);
    float4 a1 = make_float4(0.f, 0.f, 0.f, 0.f);
    int j = j0;
    for (; j + 2 <= j1; j += 2) {
        float4 e0 = esorted[j], e1 = esorted[j + 1];
        gacc(a0, yP, wtP, e0, q);
        gacc(a1, yP, wtP, e1, q);
    }
    if (j < j1) gacc(a0, yP, wtP, esorted[j], q);
    a0.x += a1.x; a0.y += a1.y; a0.z += a1.z; a0.w += a1.w;
    *(int4*)(aggP + idx) = make_int4(packsplit(a0.x), packsplit(a0.y),
                                     packsplit(a0.z), packsplit(a0.w));
}

// ---------------------------------------------------------------- pool (segment mean, no atomics)
__global__ __launch_bounds__(256)
void pool_seg_k(const int* __restrict__ hP, const int* __restrict__ mrow,
                float* __restrict__ pooled)
{
    int b = blockIdx.x;
    int t = threadIdx.x;
    if (t >= 150) return;               // cols 600..607 are pad
    int q = t << 2;
    int a = mrow[b], a1 = mrow[b + 1];
    float cnt = (float)(a1 - a);
    float4 s0 = make_float4(0.f, 0.f, 0.f, 0.f);
    float4 s1 = make_float4(0.f, 0.f, 0.f, 0.f);
    for (; a + 2 <= a1; a += 2) {
        int4 p0 = *(const int4*)(hP + (size_t)a * HP + q);
        int4 p1 = *(const int4*)(hP + (size_t)(a + 1) * HP + q);
        s0.x += unpackf(p0.x); s0.y += unpackf(p0.y);
        s0.z += unpackf(p0.z); s0.w += unpackf(p0.w);
        s1.x += unpackf(p1.x); s1.y += unpackf(p1.y);
        s1.z += unpackf(p1.z); s1.w += unpackf(p1.w);
    }
    if (a < a1) {
        int4 p0 = *(const int4*)(hP + (size_t)a * HP + q);
        s0.x += unpackf(p0.x); s0.y += unpackf(p0.y);
        s0.z += unpackf(p0.z); s0.w += unpackf(p0.w);
    }
    float inv = 1.0f / fmaxf(cnt, 1.0f);
    float4 o = make_float4((s0.x + s1.x) * inv, (s0.y + s1.y) * inv,
                           (s0.z + s1.z) * inv, (s0.w + s1.w) * inv);
    *(float4*)(pooled + (size_t)b * H_DIM + q) = o;
}

// ---------------------------------------------------------------- launch
extern "C" void kernel_launch(void* const* d_in, const int* in_sizes, int n_in,
                              void* d_out, int out_size, void* d_ws, size_t ws_size,
                              hipStream_t stream)
{
    const int*   z      = (const int*)  d_in[0];
    const float* pos    = (const float*)d_in[1];
    const int*   batch  = (const int*)  d_in[2];
    const int*   eidx   = (const int*)  d_in[3];
    const float* emb    = (const float*)d_in[4];
    const float* mlp_w1 = (const float*)d_in[5];
    const float* mlp_b1 = (const float*)d_in[6];
    const float* mlp_w2 = (const float*)d_in[7];
    const float* mlp_b2 = (const float*)d_in[8];
    const float* lin1_w = (const float*)d_in[9];
    const float* lin2_w = (const float*)d_in[10];
    const float* lin2_b = (const float*)d_in[11];
    const float* intw   = (const float*)d_in[12];
    const float* intb   = (const float*)d_in[13];
    const float* poolw  = (const float*)d_in[14];
    const float* poolb  = (const float*)d_in[15];

    float* ws = (float*)d_ws;
    const size_t NHP = (size_t)N_ATOMS * HP;       // 6,080,000
    const size_t TABALL = (size_t)L_LAYERS * M_TAB * HP;   // 3,735,552

    int*   hP    = (int*)ws;                       // NHP
    int*   y1P   = (int*)(ws + NHP);               // NHP; aliases tP, ttabA
    int*   tP    = y1P;
    int*   ttabA = y1P;                            // prep-time alias (3.7M <= NHP)
    int*   aggP  = (int*)(ws + 2 * NHP);           // NHP
    // aggP region aliases — ONLY prep-phase data that's dead before gather:
    float4* einfo  = (float4*)aggP;                          // 256,000 f
    int*    deg    = (int*)((float*)aggP + 300000);          // 10,000
    int*    cursor = (int*)((float*)aggP + 310000);          // 10,000
    int*   wtabA = (int*)(ws + 3 * NHP);           // TABALL (persistent)
    int*   rtabP = (int*)(ws + 3 * NHP + TABALL);  // M_TAB*64 = 65,536
    short* wtH   = (short*)(ws + 3 * NHP + TABALL + (size_t)M_TAB * 64);
    short* wtL   = wtH + 8985600;
    // persistent tail (NOT aliased by anything): esorted, pooled, rowptr, mrow
    float*  tailF   = (float*)(wtL + 8985600);
    float4* esorted = (float4*)tailF;                        // 256,000 f
    float*  pooled  = tailF + 256000;                        // 76,800 f (16B-aligned)
    int*    rowptr  = (int*)(tailF + 332800);                // 10,001
    int*    mrow    = rowptr + 10001;                        // 129
    // total ~31.4M 4B units = 125.5 MB

    short* w1t_h = wtH;                       short* w1t_l = wtL;
    short* w2t_h = wtH + 230400;              short* w2t_l = wtL + 230400;
    short* l1t_h = w2t_h + 6 * 600 * HP;      short* l1t_l = w2t_l + 6 * 600 * HP;
    short* l2t_h = l1t_h + 6 * 600 * HP;      short* l2t_l = l1t_l + 6 * 600 * HP;
    short* int_h = l2t_h + 6 * 600 * HP;      short* int_l = l2t_l + 6 * 600 * HP;

    const int* src = eidx;
    const int* dst = eidx + E_EDGES;

    const dim3 blk(256);
    const int QC = HP / 4;
    const dim3 gN   = mfma_grid(N_ATOMS, H_DIM);            // 1600
    const dim3 gTab = mfma_grid(L_LAYERS * M_TAB, H_DIM);   // 960

    // ---- one-time prep (einfo/deg/cursor alias aggP: dead before gather)
    edge_geom_k<<<(E_EDGES + 255) / 256, blk, 0, stream>>>(pos, src, dst, einfo);
    hipMemsetAsync(deg, 0, 2 * N_ATOMS * sizeof(int), stream);
    hist_k <<<(E_EDGES + 255) / 256, blk, 0, stream>>>(dst, deg);
    scan_k <<<1, 1024, 0, stream>>>(deg, rowptr);
    fill_k <<<(E_EDGES + 255) / 256, blk, 0, stream>>>(dst, einfo, rowptr, cursor, esorted);
    bounds_k <<<1, 256, 0, stream>>>(batch, mrow);
    init_h_k <<<(N_ATOMS * QC + 255) / 256, blk, 0, stream>>>(z, emb, hP);
    rbf_tab_k<<<(M_TAB * 64 + 255) / 256,   blk, 0, stream>>>(rtabP);
    wts_w1_k  <<<dim3(1, 10, 6),   blk, 0, stream>>>(mlp_w1, w1t_h, w1t_l);
    wts_big_k <<<dim3(10, 10, 24), blk, 0, stream>>>(
        mlp_w2, lin1_w, lin2_w, intw,
        w2t_h, w2t_l, l1t_h, l1t_l, l2t_h, l2t_l, int_h, int_l);

    // ---- all 6 layers' filter tables in 2 batched slab GEMMs
    // ttabA = ssp(rtab @ w1[l] + b1[l]) stacked  [6144 x 600], K=64
    gemm_tab<true, true><<<gTab, blk, 0, stream>>>(
        rtabP, 64, w1t_h, w1t_l, 64, 600 * 64, mlp_b1,
        ttabA, L_LAYERS * M_TAB, 64, H_DIM);
    // wtabA = ttab @ w2[l] + b2[l] stacked       [6144 x 600], K=HP
    gemm_tab<false, false><<<gTab, blk, 0, stream>>>(
        ttabA, HP, w2t_h, w2t_l, HP, 600 * HP, mlp_b2,
        wtabA, L_LAYERS * M_TAB, HP, H_DIM);

    for (int k = 0; k < L_LAYERS; ++k) {
        const float* l2b = lin2_b + (size_t)k * H_DIM;
        const float* ib  = intb   + (size_t)k * H_DIM;
        const short* l1h = l1t_h + (size_t)k * H_DIM * HP;
        const short* l1l = l1t_l + (size_t)k * H_DIM * HP;
        const short* l2h = l2t_h + (size_t)k * H_DIM * HP;
        const short* l2l = l2t_l + (size_t)k * H_DIM * HP;
        const short* ih  = int_h + (size_t)k * H_DIM * HP;
        const short* il  = int_l + (size_t)k * H_DIM * HP;
        const int*   wtP = wtabA + (size_t)k * M_TAB * HP;

        // y1P = packsplit(h @ lin1)
        gemm_mfma<false, false, false><<<gN, blk, 0, stream>>>(
            hP, HP, l1h, l1l, HP, nullptr, y1P, N_ATOMS, HP, H_DIM);
        // aggP = packsplit(CSR-gather(y1 * W(d) * C))
        gather_k<<<(N_ATOMS * QC + 255) / 256, blk, 0, stream>>>(
            y1P, wtP, rowptr, esorted, aggP);
        // tP = packsplit(ssp(agg @ lin2 + b))   (aliases y1P)
        gemm_mfma<true, true, false><<<gN, blk, 0, stream>>>(
            aggP, HP, l2h, l2l, HP, l2b, tP, N_ATOMS, HP, H_DIM);
        // hP = packsplit(unpack(hP) + t @ int_w + ib)
        gemm_mfma<true, false, true><<<gN, blk, 0, stream>>>(
            tP, HP, ih, il, HP, ib, hP, N_ATOMS, HP, H_DIM);
    }

    // segment-mean pool (sorted batch, no atomics), then out = pooled @ pool_w + b
    pool_seg_k<<<B_MOLS, blk, 0, stream>>>(hP, mrow, pooled);
    gemm_k<true><<<dim3((H_DIM + BN - 1) / BN, (B_MOLS + BM - 1) / BM), blk, 0, stream>>>(
        pooled, H_DIM, poolw, poolb, (float*)d_out, B_MOLS, H_DIM, H_DIM);
}